// Round 1
// baseline (286.385 us; speedup 1.0000x reference)
//
#include <hip/hip_runtime.h>

#define BSZ 8
#define SEQL 1024
#define CHN 1024
#define M1 (BSZ*SEQL)

#define BM 128
#define BN 64
#define BK 32
#define TPAD 136

typedef __attribute__((ext_vector_type(8))) short bf16x8;
typedef __attribute__((ext_vector_type(4))) float f32x4;
typedef __attribute__((ext_vector_type(4))) unsigned short us4;
typedef __attribute__((ext_vector_type(8))) unsigned short us8;

static __device__ __forceinline__ unsigned short f2bf(float f){
  unsigned int u = __float_as_uint(f);
  u += 0x7fffu + ((u >> 16) & 1u);
  return (unsigned short)(u >> 16);
}
static __device__ __forceinline__ float bf2f(unsigned short h){
  return __uint_as_float(((unsigned int)h) << 16);
}
static __device__ __forceinline__ void gload16(const void* g, void* l){
  __builtin_amdgcn_global_load_lds((const __attribute__((address_space(1))) void*)g,
                                   (__attribute__((address_space(3))) void*)l,
                                   16, 0, 0);
}

// ---------------- prep: fp32 -> bf16 conversions + exp(bias) ----------------
__global__ void prep_kernel(const float* __restrict__ x, const float* __restrict__ wq,
                            const float* __restrict__ wk, const float* __restrict__ wv,
                            const float* __restrict__ bias,
                            unsigned short* __restrict__ xb, unsigned short* __restrict__ wqb,
                            unsigned short* __restrict__ wkb, unsigned short* __restrict__ wvb,
                            unsigned short* __restrict__ ebb)
{
  const int NX = M1 * CHN;          // 8388608
  const int NW = CHN * CHN;         // 1048576
  const int total4 = (NX + 3 * NW + SEQL * SEQL) >> 2;
  for (int i = blockIdx.x * blockDim.x + threadIdx.x; i < total4;
       i += gridDim.x * blockDim.x) {
    int e = i << 2;
    const float* src; unsigned short* dst; int off; bool ex = false;
    if (e < NX)               { src = x;    dst = xb;  off = e; }
    else if (e < NX + NW)     { src = wq;   dst = wqb; off = e - NX; }
    else if (e < NX + 2 * NW) { src = wk;   dst = wkb; off = e - (NX + NW); }
    else if (e < NX + 3 * NW) { src = wv;   dst = wvb; off = e - (NX + 2 * NW); }
    else                      { src = bias; dst = ebb; off = e - (NX + 3 * NW); ex = true; }
    float4 v = *reinterpret_cast<const float4*>(src + off);
    if (ex) { v.x = expf(v.x); v.y = expf(v.y); v.z = expf(v.z); v.w = expf(v.w); }
    us4 o; o.x = f2bf(v.x); o.y = f2bf(v.y); o.z = f2bf(v.z); o.w = f2bf(v.w);
    *reinterpret_cast<us4*>(dst + off) = o;
  }
}

// ---------------- gemm_qkv: q,k,v = X @ W{q,k,v}^T (+bias), fused epilogue ----------------
// Writes: Qb[m][c] (bf16), EKT[(b*C+c)][s] = exp(k) (bf16), EKVT = exp(k)*v (bf16, same layout)
__global__ __launch_bounds__(256) void gemm_qkv(
    const unsigned short* __restrict__ Xb,
    const unsigned short* __restrict__ Wq,
    const unsigned short* __restrict__ Wk,
    const unsigned short* __restrict__ Wv,
    const float* __restrict__ bq,
    const float* __restrict__ bk,
    const float* __restrict__ bv,
    unsigned short* __restrict__ Qb,
    unsigned short* __restrict__ EKT,
    unsigned short* __restrict__ EKVT)
{
  __shared__ unsigned short lds[2 * 64 * TPAD];  // 34816 B; staging uses first 10240 shorts
  unsigned short* As = lds;                       // [BM][BK]

  const int tid = threadIdx.x;
  const int lane = tid & 63;
  const int wid = tid >> 6;
  const int wm = wid >> 1;
  const int wn = wid & 1;
  const int m0 = blockIdx.y * BM;
  const int n0 = blockIdx.x * BN;

  // staging addresses (A: 2x16B per thread, B: 1x16B per thread per matrix)
  const int linA0 = tid * 16;
  const int linA1 = 4096 + tid * 16;
  const unsigned short* gA0 = Xb + (m0 + (linA0 >> 6)) * CHN + ((linA0 & 63) >> 1);
  const unsigned short* gA1 = Xb + (m0 + (linA1 >> 6)) * CHN + ((linA1 & 63) >> 1);
  unsigned short* lA0 = As + (linA0 >> 1);
  unsigned short* lA1 = As + (linA1 >> 1);

  const int linB = tid * 16;
  const int rowB = linB >> 6;
  const int colB = (linB & 63) >> 1;
  const unsigned short* gB0 = Wq + (n0 + rowB) * CHN + colB;
  const unsigned short* gB1 = Wk + (n0 + rowB) * CHN + colB;
  const unsigned short* gB2 = Wv + (n0 + rowB) * CHN + colB;
  unsigned short* lB0 = lds + 4096 + (linB >> 1);
  unsigned short* lB1 = lds + 6144 + (linB >> 1);
  unsigned short* lB2 = lds + 8192 + (linB >> 1);

  int aOff[4], bOff[2];
#pragma unroll
  for (int mi = 0; mi < 4; mi++)
    aOff[mi] = (wm * 64 + mi * 16 + (lane & 15)) * BK + (lane >> 4) * 8;
#pragma unroll
  for (int ni = 0; ni < 2; ni++)
    bOff[ni] = (wn * 32 + ni * 16 + (lane & 15)) * BK + (lane >> 4) * 8;

  f32x4 accq[4][2] = {}, acck[4][2] = {}, accv[4][2] = {};

  for (int kk = 0; kk < CHN; kk += BK) {
    gload16(gA0 + kk, lA0);
    gload16(gA1 + kk, lA1);
    gload16(gB0 + kk, lB0);
    gload16(gB1 + kk, lB1);
    gload16(gB2 + kk, lB2);
    __syncthreads();
    bf16x8 af[4];
#pragma unroll
    for (int mi = 0; mi < 4; mi++)
      af[mi] = *reinterpret_cast<const bf16x8*>(As + aOff[mi]);
#pragma unroll
    for (int ni = 0; ni < 2; ni++) {
      bf16x8 b0 = *reinterpret_cast<const bf16x8*>(lds + 4096 + bOff[ni]);
      bf16x8 b1 = *reinterpret_cast<const bf16x8*>(lds + 6144 + bOff[ni]);
      bf16x8 b2 = *reinterpret_cast<const bf16x8*>(lds + 8192 + bOff[ni]);
#pragma unroll
      for (int mi = 0; mi < 4; mi++) {
        accq[mi][ni] = __builtin_amdgcn_mfma_f32_16x16x32_bf16(af[mi], b0, accq[mi][ni], 0, 0, 0);
        acck[mi][ni] = __builtin_amdgcn_mfma_f32_16x16x32_bf16(af[mi], b1, acck[mi][ni], 0, 0, 0);
        accv[mi][ni] = __builtin_amdgcn_mfma_f32_16x16x32_bf16(af[mi], b2, accv[mi][ni], 0, 0, 0);
      }
    }
    __syncthreads();
  }

  // ---- epilogue ----
  const int bIdx = m0 >> 10;
  const int s0 = m0 & 1023;
  const int rbase = (lane >> 4) * 4;

  float bqv[2], bkv[2], bvv[2];
#pragma unroll
  for (int ni = 0; ni < 2; ni++) {
    int c = n0 + wn * 32 + ni * 16 + (lane & 15);
    bqv[ni] = bq[c]; bkv[ni] = bk[c]; bvv[ni] = bv[c];
  }

  // q write + transpose ek/ekv into LDS (safe: loop ended with __syncthreads)
#pragma unroll
  for (int mi = 0; mi < 4; mi++) {
#pragma unroll
    for (int ni = 0; ni < 2; ni++) {
      int nloc = wn * 32 + ni * 16 + (lane & 15);
#pragma unroll
      for (int r = 0; r < 4; r++) {
        int mrow = wm * 64 + mi * 16 + rbase + r;
        float qv = accq[mi][ni][r] + bqv[ni];
        Qb[(m0 + mrow) * CHN + (n0 + nloc)] = f2bf(qv);
        float ekf = expf(acck[mi][ni][r] + bkv[ni]);
        float kvf = ekf * (accv[mi][ni][r] + bvv[ni]);
        lds[nloc * TPAD + mrow] = f2bf(ekf);
        lds[64 * TPAD + nloc * TPAD + mrow] = f2bf(kvf);
      }
    }
  }
  __syncthreads();
  // coalesced transposed writes: rows are (b*C+c), 128 s-contiguous bf16 each
#pragma unroll
  for (int it = 0; it < 4; it++) {
    int ch = it * 256 + tid;
    int nloc = ch >> 4;
    int c8 = ch & 15;
    us8 vek  = *reinterpret_cast<const us8*>(lds + nloc * TPAD + c8 * 8);
    us8 vekv = *reinterpret_cast<const us8*>(lds + 64 * TPAD + nloc * TPAD + c8 * 8);
    int gi = (bIdx * CHN + n0 + nloc) * SEQL + s0 + c8 * 8;
    *reinterpret_cast<us8*>(EKT + gi) = vek;
    *reinterpret_cast<us8*>(EKVT + gi) = vekv;
  }
}

// ---------------- gemm_aft: num/den = exp(bias) @ {EKV, EK}; out = sigmoid(q)*num/den ----------------
__global__ __launch_bounds__(256) void gemm_aft(
    const unsigned short* __restrict__ EB,
    const unsigned short* __restrict__ EKT,
    const unsigned short* __restrict__ EKVT,
    const unsigned short* __restrict__ Qb,
    float* __restrict__ out)
{
  __shared__ unsigned short lds[BM * BK + 2 * BN * BK];  // 8192 shorts = 16 KiB
  unsigned short* As = lds;

  const int tid = threadIdx.x;
  const int lane = tid & 63;
  const int wid = tid >> 6;
  const int wm = wid >> 1;
  const int wn = wid & 1;
  const int t0 = blockIdx.y * BM;
  const int n0 = blockIdx.x * BN;

  const int linA0 = tid * 16;
  const int linA1 = 4096 + tid * 16;
  const unsigned short* gA0 = EB + (t0 + (linA0 >> 6)) * SEQL + ((linA0 & 63) >> 1);
  const unsigned short* gA1 = EB + (t0 + (linA1 >> 6)) * SEQL + ((linA1 & 63) >> 1);
  unsigned short* lA0 = As + (linA0 >> 1);
  unsigned short* lA1 = As + (linA1 >> 1);

  const int linB = tid * 16;
  const int rowB = linB >> 6;
  const int colB = (linB & 63) >> 1;
  const unsigned short* gB0 = EKT + (n0 + rowB) * SEQL + colB;   // -> den
  const unsigned short* gB1 = EKVT + (n0 + rowB) * SEQL + colB;  // -> num
  unsigned short* lB0 = lds + 4096 + (linB >> 1);
  unsigned short* lB1 = lds + 6144 + (linB >> 1);

  int aOff[4], bOff[2];
#pragma unroll
  for (int mi = 0; mi < 4; mi++)
    aOff[mi] = (wm * 64 + mi * 16 + (lane & 15)) * BK + (lane >> 4) * 8;
#pragma unroll
  for (int ni = 0; ni < 2; ni++)
    bOff[ni] = (wn * 32 + ni * 16 + (lane & 15)) * BK + (lane >> 4) * 8;

  f32x4 accd[4][2] = {}, accn[4][2] = {};

  for (int kk = 0; kk < SEQL; kk += BK) {
    gload16(gA0 + kk, lA0);
    gload16(gA1 + kk, lA1);
    gload16(gB0 + kk, lB0);
    gload16(gB1 + kk, lB1);
    __syncthreads();
    bf16x8 af[4];
#pragma unroll
    for (int mi = 0; mi < 4; mi++)
      af[mi] = *reinterpret_cast<const bf16x8*>(As + aOff[mi]);
#pragma unroll
    for (int ni = 0; ni < 2; ni++) {
      bf16x8 b0 = *reinterpret_cast<const bf16x8*>(lds + 4096 + bOff[ni]);
      bf16x8 b1 = *reinterpret_cast<const bf16x8*>(lds + 6144 + bOff[ni]);
#pragma unroll
      for (int mi = 0; mi < 4; mi++) {
        accd[mi][ni] = __builtin_amdgcn_mfma_f32_16x16x32_bf16(af[mi], b0, accd[mi][ni], 0, 0, 0);
        accn[mi][ni] = __builtin_amdgcn_mfma_f32_16x16x32_bf16(af[mi], b1, accn[mi][ni], 0, 0, 0);
      }
    }
    __syncthreads();
  }

  const int rbase = (lane >> 4) * 4;
#pragma unroll
  for (int mi = 0; mi < 4; mi++) {
#pragma unroll
    for (int ni = 0; ni < 2; ni++) {
      int nloc = wn * 32 + ni * 16 + (lane & 15);
      int n = n0 + nloc;
      int b = n >> 10;
      int c = n & 1023;
#pragma unroll
      for (int r = 0; r < 4; r++) {
        int t = t0 + wm * 64 + mi * 16 + rbase + r;
        float num = accn[mi][ni][r];
        float den = accd[mi][ni][r];
        float qv = bf2f(Qb[(b * SEQL + t) * CHN + c]);
        float sig = 1.0f / (1.0f + expf(-qv));
        out[(b * SEQL + t) * CHN + c] = sig * num / den;
      }
    }
  }
}

extern "C" void kernel_launch(void* const* d_in, const int* in_sizes, int n_in,
                              void* d_out, int out_size, void* d_ws, size_t ws_size,
                              hipStream_t stream) {
  (void)in_sizes; (void)n_in; (void)out_size; (void)ws_size;
  const float* x    = (const float*)d_in[0];
  const float* wq   = (const float*)d_in[1];
  const float* wk   = (const float*)d_in[2];
  const float* wv   = (const float*)d_in[3];
  const float* bq   = (const float*)d_in[4];
  const float* bk   = (const float*)d_in[5];
  const float* bv   = (const float*)d_in[6];
  const float* bias = (const float*)d_in[7];
  float* out = (float*)d_out;

  char* ws = (char*)d_ws;
  const size_t MB = 1024 * 1024;
  unsigned short* Xb   = (unsigned short*)(ws);
  unsigned short* Wqb  = (unsigned short*)(ws + 16 * MB);
  unsigned short* Wkb  = (unsigned short*)(ws + 18 * MB);
  unsigned short* Wvb  = (unsigned short*)(ws + 20 * MB);
  unsigned short* EBb  = (unsigned short*)(ws + 22 * MB);
  unsigned short* Qb   = (unsigned short*)(ws + 24 * MB);
  unsigned short* EKT  = (unsigned short*)(ws + 40 * MB);
  unsigned short* EKVT = (unsigned short*)(ws + 56 * MB);

  prep_kernel<<<2048, 256, 0, stream>>>(x, wq, wk, wv, bias, Xb, Wqb, Wkb, Wvb, EBb);
  gemm_qkv<<<dim3(CHN / BN, M1 / BM), 256, 0, stream>>>(Xb, Wqb, Wkb, Wvb, bq, bk, bv,
                                                        Qb, EKT, EKVT);
  gemm_aft<<<dim3((BSZ * CHN) / BN, SEQL / BM), 256, 0, stream>>>(EBb, EKT, EKVT, Qb, out);
}

// Round 2
// 233.492 us; speedup vs baseline: 1.2265x; 1.2265x over previous
//
#include <hip/hip_runtime.h>

#define BSZ 8
#define SEQL 1024
#define CHN 1024
#define M1 (BSZ*SEQL)

typedef __attribute__((ext_vector_type(8))) short bf16x8;
typedef __attribute__((ext_vector_type(4))) float f32x4;
typedef __attribute__((ext_vector_type(4))) unsigned short us4;
typedef __attribute__((ext_vector_type(8))) unsigned short us8;

static __device__ __forceinline__ unsigned short f2bf(float f){
  unsigned int u = __float_as_uint(f);
  u += 0x7fffu + ((u >> 16) & 1u);
  return (unsigned short)(u >> 16);
}
static __device__ __forceinline__ float bf2f(unsigned short h){
  return __uint_as_float(((unsigned int)h) << 16);
}
static __device__ __forceinline__ void gload16(const void* g, void* l){
  __builtin_amdgcn_global_load_lds((const __attribute__((address_space(1))) void*)g,
                                   (__attribute__((address_space(3))) void*)l,
                                   16, 0, 0);
}
// 16B-chunk XOR swizzle within a 64B row of a [rows][32-short] staging tile.
static __device__ __forceinline__ int swzc(int row, int chunk){
  return chunk ^ ((row >> 1) & 3);
}

// ---------------- prep: fp32 -> bf16 conversions + exp(bias) ----------------
__global__ void prep_kernel(const float* __restrict__ x, const float* __restrict__ wq,
                            const float* __restrict__ wk, const float* __restrict__ wv,
                            const float* __restrict__ bias,
                            unsigned short* __restrict__ xb, unsigned short* __restrict__ wqb,
                            unsigned short* __restrict__ wkb, unsigned short* __restrict__ wvb,
                            unsigned short* __restrict__ ebb)
{
  const int NX = M1 * CHN;
  const int NW = CHN * CHN;
  const int total4 = (NX + 3 * NW + SEQL * SEQL) >> 2;
  for (int i = blockIdx.x * blockDim.x + threadIdx.x; i < total4;
       i += gridDim.x * blockDim.x) {
    int e = i << 2;
    const float* src; unsigned short* dst; int off; bool ex = false;
    if (e < NX)               { src = x;    dst = xb;  off = e; }
    else if (e < NX + NW)     { src = wq;   dst = wqb; off = e - NX; }
    else if (e < NX + 2 * NW) { src = wk;   dst = wkb; off = e - (NX + NW); }
    else if (e < NX + 3 * NW) { src = wv;   dst = wvb; off = e - (NX + 2 * NW); }
    else                      { src = bias; dst = ebb; off = e - (NX + 3 * NW); ex = true; }
    float4 v = *reinterpret_cast<const float4*>(src + off);
    if (ex) { v.x = expf(v.x); v.y = expf(v.y); v.z = expf(v.z); v.w = expf(v.w); }
    us4 o; o.x = f2bf(v.x); o.y = f2bf(v.y); o.z = f2bf(v.z); o.w = f2bf(v.w);
    *reinterpret_cast<us4*>(dst + off) = o;
  }
}

// ---------------- gemm_q: Q = X @ Wq^T + bq -> bf16 (m97-class 128x128) ----------------
__global__ __launch_bounds__(256) void gemm_q(
    const unsigned short* __restrict__ Xb, const unsigned short* __restrict__ Wq,
    const float* __restrict__ bq, unsigned short* __restrict__ Qb)
{
  __shared__ unsigned short lds[8192];   // A 128x32 | B 128x32 (16 KiB)
  const int tid = threadIdx.x;
  const int lane = tid & 63;
  const int wm = tid >> 7;
  const int wn = (tid >> 6) & 1;
  const int nwg = gridDim.x;             // 512
  const int lid = blockIdx.x;
  const int sid = (lid & 7) * (nwg >> 3) + (lid >> 3);
  const int m0 = (sid & 63) * 128;
  const int n0 = (sid >> 6) * 128;

  const int linA0 = tid * 16, linA1 = 4096 + tid * 16;
  const int rA0 = linA0 >> 6, cA0 = (linA0 >> 4) & 3;
  const int rA1 = linA1 >> 6, cA1 = (linA1 >> 4) & 3;
  const unsigned short* gA0 = Xb + (m0 + rA0) * CHN + swzc(rA0, cA0) * 8;
  const unsigned short* gA1 = Xb + (m0 + rA1) * CHN + swzc(rA1, cA1) * 8;
  const unsigned short* gB0 = Wq + (n0 + rA0) * CHN + swzc(rA0, cA0) * 8;
  const unsigned short* gB1 = Wq + (n0 + rA1) * CHN + swzc(rA1, cA1) * 8;
  unsigned short* lA0 = lds + (linA0 >> 1);
  unsigned short* lA1 = lds + (linA1 >> 1);
  unsigned short* lB0 = lds + 4096 + (linA0 >> 1);
  unsigned short* lB1 = lds + 4096 + (linA1 >> 1);

  int aOff[4], bOff[4];
#pragma unroll
  for (int mi = 0; mi < 4; mi++) {
    int r = wm * 64 + mi * 16 + (lane & 15);
    aOff[mi] = r * 32 + swzc(r, lane >> 4) * 8;
  }
#pragma unroll
  for (int ni = 0; ni < 4; ni++) {
    int r = wn * 64 + ni * 16 + (lane & 15);
    bOff[ni] = 4096 + r * 32 + swzc(r, lane >> 4) * 8;
  }

  f32x4 acc[4][4] = {};
  for (int kk = 0; kk < CHN; kk += 32) {
    gload16(gA0 + kk, lA0); gload16(gA1 + kk, lA1);
    gload16(gB0 + kk, lB0); gload16(gB1 + kk, lB1);
    __syncthreads();
    bf16x8 af[4], bf[4];
#pragma unroll
    for (int mi = 0; mi < 4; mi++) af[mi] = *reinterpret_cast<const bf16x8*>(lds + aOff[mi]);
#pragma unroll
    for (int ni = 0; ni < 4; ni++) bf[ni] = *reinterpret_cast<const bf16x8*>(lds + bOff[ni]);
#pragma unroll
    for (int ni = 0; ni < 4; ni++)
#pragma unroll
      for (int mi = 0; mi < 4; mi++)
        acc[mi][ni] = __builtin_amdgcn_mfma_f32_16x16x32_bf16(af[mi], bf[ni], acc[mi][ni], 0, 0, 0);
    __syncthreads();
  }

  const int rb = (lane >> 4) * 4;
  float bqv[4];
#pragma unroll
  for (int ni = 0; ni < 4; ni++) bqv[ni] = bq[n0 + wn * 64 + ni * 16 + (lane & 15)];
#pragma unroll
  for (int mi = 0; mi < 4; mi++)
#pragma unroll
    for (int ni = 0; ni < 4; ni++)
#pragma unroll
      for (int r = 0; r < 4; r++) {
        int mrow = m0 + wm * 64 + mi * 16 + rb + r;
        int col  = n0 + wn * 64 + ni * 16 + (lane & 15);
        Qb[mrow * CHN + col] = f2bf(acc[mi][ni][r] + bqv[ni]);
      }
}

// ---------------- gemm_kv: k,v = X @ W{k,v}^T + b; write EKT/EKVT transposed ----------------
__global__ __launch_bounds__(256) void gemm_kv(
    const unsigned short* __restrict__ Xb,
    const unsigned short* __restrict__ Wk, const unsigned short* __restrict__ Wv,
    const float* __restrict__ bk, const float* __restrict__ bv,
    unsigned short* __restrict__ EKT, unsigned short* __restrict__ EKVT)
{
  __shared__ unsigned short lds[8704];   // staging 8192 shorts; transpose 64x136=8704
  const int tid = threadIdx.x;
  const int lane = tid & 63;
  const int wm = tid >> 7;
  const int wn = (tid >> 6) & 1;
  const int nwg = gridDim.x;             // 1024
  const int lid = blockIdx.x;
  const int sid = (lid & 7) * (nwg >> 3) + (lid >> 3);
  const int m0 = (sid & 63) * 128;
  const int n0 = (sid >> 6) * 64;

  const int linA0 = tid * 16, linA1 = 4096 + tid * 16;
  const int rA0 = linA0 >> 6, cA0 = (linA0 >> 4) & 3;
  const int rA1 = linA1 >> 6, cA1 = (linA1 >> 4) & 3;
  const unsigned short* gA0 = Xb + (m0 + rA0) * CHN + swzc(rA0, cA0) * 8;
  const unsigned short* gA1 = Xb + (m0 + rA1) * CHN + swzc(rA1, cA1) * 8;
  const int rB = tid >> 2, cB = tid & 3;
  const unsigned short* gBk = Wk + (n0 + rB) * CHN + swzc(rB, cB) * 8;
  const unsigned short* gBv = Wv + (n0 + rB) * CHN + swzc(rB, cB) * 8;
  unsigned short* lA0 = lds + (linA0 >> 1);
  unsigned short* lA1 = lds + (linA1 >> 1);
  unsigned short* lBk = lds + 4096 + tid * 8;
  unsigned short* lBv = lds + 6144 + tid * 8;

  int aOff[4], bOff[2];
#pragma unroll
  for (int mi = 0; mi < 4; mi++) {
    int r = wm * 64 + mi * 16 + (lane & 15);
    aOff[mi] = r * 32 + swzc(r, lane >> 4) * 8;
  }
#pragma unroll
  for (int ni = 0; ni < 2; ni++) {
    int r = wn * 32 + ni * 16 + (lane & 15);
    bOff[ni] = r * 32 + swzc(r, lane >> 4) * 8;
  }

  f32x4 acck[4][2] = {}, accv[4][2] = {};
  for (int kk = 0; kk < CHN; kk += 32) {
    gload16(gA0 + kk, lA0); gload16(gA1 + kk, lA1);
    gload16(gBk + kk, lBk); gload16(gBv + kk, lBv);
    __syncthreads();
    bf16x8 af[4];
#pragma unroll
    for (int mi = 0; mi < 4; mi++) af[mi] = *reinterpret_cast<const bf16x8*>(lds + aOff[mi]);
#pragma unroll
    for (int ni = 0; ni < 2; ni++) {
      bf16x8 bk_ = *reinterpret_cast<const bf16x8*>(lds + 4096 + bOff[ni]);
      bf16x8 bv_ = *reinterpret_cast<const bf16x8*>(lds + 6144 + bOff[ni]);
#pragma unroll
      for (int mi = 0; mi < 4; mi++) {
        acck[mi][ni] = __builtin_amdgcn_mfma_f32_16x16x32_bf16(af[mi], bk_, acck[mi][ni], 0, 0, 0);
        accv[mi][ni] = __builtin_amdgcn_mfma_f32_16x16x32_bf16(af[mi], bv_, accv[mi][ni], 0, 0, 0);
      }
    }
    __syncthreads();
  }

  // ---- epilogue: ek = exp(k+bk), ekv = ek*(v+bv); transposed bf16 writes ----
  const int bIdx = m0 >> 10;
  const int s0 = m0 & 1023;
  const int rb = (lane >> 4) * 4;
  float bkv[2], bvv[2];
#pragma unroll
  for (int ni = 0; ni < 2; ni++) {
    int c = n0 + wn * 32 + ni * 16 + (lane & 15);
    bkv[ni] = bk[c]; bvv[ni] = bv[c];
  }
#pragma unroll
  for (int mi = 0; mi < 4; mi++)
#pragma unroll
    for (int ni = 0; ni < 2; ni++)
#pragma unroll
      for (int r = 0; r < 4; r++) {
        float ekf = expf(acck[mi][ni][r] + bkv[ni]);
        acck[mi][ni][r] = ekf;
        accv[mi][ni][r] = ekf * (accv[mi][ni][r] + bvv[ni]);
      }
  // pass 1: ek -> LDS transpose -> EKT
#pragma unroll
  for (int mi = 0; mi < 4; mi++)
#pragma unroll
    for (int ni = 0; ni < 2; ni++) {
      int nloc = wn * 32 + ni * 16 + (lane & 15);
#pragma unroll
      for (int r = 0; r < 4; r++)
        lds[nloc * 136 + wm * 64 + mi * 16 + rb + r] = f2bf(acck[mi][ni][r]);
    }
  __syncthreads();
#pragma unroll
  for (int it = 0; it < 4; it++) {
    int ch = it * 256 + tid;
    int nloc = ch >> 4, c8 = ch & 15;
    us8 v = *reinterpret_cast<const us8*>(lds + nloc * 136 + c8 * 8);
    *reinterpret_cast<us8*>(EKT + (bIdx * CHN + n0 + nloc) * SEQL + s0 + c8 * 8) = v;
  }
  __syncthreads();
  // pass 2: ekv -> LDS transpose -> EKVT
#pragma unroll
  for (int mi = 0; mi < 4; mi++)
#pragma unroll
    for (int ni = 0; ni < 2; ni++) {
      int nloc = wn * 32 + ni * 16 + (lane & 15);
#pragma unroll
      for (int r = 0; r < 4; r++)
        lds[nloc * 136 + wm * 64 + mi * 16 + rb + r] = f2bf(accv[mi][ni][r]);
    }
  __syncthreads();
#pragma unroll
  for (int it = 0; it < 4; it++) {
    int ch = it * 256 + tid;
    int nloc = ch >> 4, c8 = ch & 15;
    us8 v = *reinterpret_cast<const us8*>(lds + nloc * 136 + c8 * 8);
    *reinterpret_cast<us8*>(EKVT + (bIdx * CHN + n0 + nloc) * SEQL + s0 + c8 * 8) = v;
  }
}

// ---------------- gemm_aft: num/den = EB @ {EKVT,EKT}^T; out = sigmoid(q)*num/den ----------------
__global__ __launch_bounds__(256) void gemm_aft(
    const unsigned short* __restrict__ EB,
    const unsigned short* __restrict__ EKT, const unsigned short* __restrict__ EKVT,
    const unsigned short* __restrict__ Qb, float* __restrict__ out)
{
  __shared__ unsigned short lds[8192];   // A 128x32 | Bd 64x32 | Bn 64x32
  const int tid = threadIdx.x;
  const int lane = tid & 63;
  const int wm = tid >> 7;
  const int wn = (tid >> 6) & 1;
  const int nwg = gridDim.x;             // 1024
  const int lid = blockIdx.x;
  const int sid = (lid & 7) * (nwg >> 3) + (lid >> 3);
  const int t0 = (sid & 7) * 128;
  const int n0 = (sid >> 3) * 64;

  const int linA0 = tid * 16, linA1 = 4096 + tid * 16;
  const int rA0 = linA0 >> 6, cA0 = (linA0 >> 4) & 3;
  const int rA1 = linA1 >> 6, cA1 = (linA1 >> 4) & 3;
  const unsigned short* gA0 = EB + (t0 + rA0) * SEQL + swzc(rA0, cA0) * 8;
  const unsigned short* gA1 = EB + (t0 + rA1) * SEQL + swzc(rA1, cA1) * 8;
  const int rB = tid >> 2, cB = tid & 3;
  const unsigned short* gBd = EKT + (n0 + rB) * SEQL + swzc(rB, cB) * 8;
  const unsigned short* gBn = EKVT + (n0 + rB) * SEQL + swzc(rB, cB) * 8;
  unsigned short* lA0 = lds + (linA0 >> 1);
  unsigned short* lA1 = lds + (linA1 >> 1);
  unsigned short* lBd = lds + 4096 + tid * 8;
  unsigned short* lBn = lds + 6144 + tid * 8;

  int aOff[4], bOff[2];
#pragma unroll
  for (int mi = 0; mi < 4; mi++) {
    int r = wm * 64 + mi * 16 + (lane & 15);
    aOff[mi] = r * 32 + swzc(r, lane >> 4) * 8;
  }
#pragma unroll
  for (int ni = 0; ni < 2; ni++) {
    int r = wn * 32 + ni * 16 + (lane & 15);
    bOff[ni] = r * 32 + swzc(r, lane >> 4) * 8;
  }

  f32x4 accd[4][2] = {}, accn[4][2] = {};
  for (int kk = 0; kk < SEQL; kk += 32) {
    gload16(gA0 + kk, lA0); gload16(gA1 + kk, lA1);
    gload16(gBd + kk, lBd); gload16(gBn + kk, lBn);
    __syncthreads();
    bf16x8 af[4];
#pragma unroll
    for (int mi = 0; mi < 4; mi++) af[mi] = *reinterpret_cast<const bf16x8*>(lds + aOff[mi]);
#pragma unroll
    for (int ni = 0; ni < 2; ni++) {
      bf16x8 bd_ = *reinterpret_cast<const bf16x8*>(lds + 4096 + bOff[ni]);
      bf16x8 bn_ = *reinterpret_cast<const bf16x8*>(lds + 6144 + bOff[ni]);
#pragma unroll
      for (int mi = 0; mi < 4; mi++) {
        accd[mi][ni] = __builtin_amdgcn_mfma_f32_16x16x32_bf16(af[mi], bd_, accd[mi][ni], 0, 0, 0);
        accn[mi][ni] = __builtin_amdgcn_mfma_f32_16x16x32_bf16(af[mi], bn_, accn[mi][ni], 0, 0, 0);
      }
    }
    __syncthreads();
  }

  const int rb = (lane >> 4) * 4;
#pragma unroll
  for (int mi = 0; mi < 4; mi++)
#pragma unroll
    for (int ni = 0; ni < 2; ni++) {
      int nloc = wn * 32 + ni * 16 + (lane & 15);
      int n = n0 + nloc;
      int b = n >> 10, c = n & 1023;
#pragma unroll
      for (int r = 0; r < 4; r++) {
        int t = t0 + wm * 64 + mi * 16 + rb + r;
        float qv = bf2f(Qb[(b * SEQL + t) * CHN + c]);
        float sig = 1.0f / (1.0f + expf(-qv));
        out[(b * SEQL + t) * CHN + c] = sig * accn[mi][ni][r] / accd[mi][ni][r];
      }
    }
}

extern "C" void kernel_launch(void* const* d_in, const int* in_sizes, int n_in,
                              void* d_out, int out_size, void* d_ws, size_t ws_size,
                              hipStream_t stream) {
  (void)in_sizes; (void)n_in; (void)out_size; (void)ws_size;
  const float* x    = (const float*)d_in[0];
  const float* wq   = (const float*)d_in[1];
  const float* wk   = (const float*)d_in[2];
  const float* wv   = (const float*)d_in[3];
  const float* bq   = (const float*)d_in[4];
  const float* bk   = (const float*)d_in[5];
  const float* bv   = (const float*)d_in[6];
  const float* bias = (const float*)d_in[7];
  float* out = (float*)d_out;

  char* ws = (char*)d_ws;
  const size_t MB = 1024 * 1024;
  unsigned short* Xb   = (unsigned short*)(ws);
  unsigned short* Wqb  = (unsigned short*)(ws + 16 * MB);
  unsigned short* Wkb  = (unsigned short*)(ws + 18 * MB);
  unsigned short* Wvb  = (unsigned short*)(ws + 20 * MB);
  unsigned short* EBb  = (unsigned short*)(ws + 22 * MB);
  unsigned short* Qb   = (unsigned short*)(ws + 24 * MB);
  unsigned short* EKT  = (unsigned short*)(ws + 40 * MB);
  unsigned short* EKVT = (unsigned short*)(ws + 56 * MB);

  prep_kernel<<<2048, 256, 0, stream>>>(x, wq, wk, wv, bias, Xb, Wqb, Wkb, Wvb, EBb);
  gemm_q<<<512, 256, 0, stream>>>(Xb, Wqb, bq, Qb);
  gemm_kv<<<1024, 256, 0, stream>>>(Xb, Wkb, Wvb, bk, bv, EKT, EKVT);
  gemm_aft<<<1024, 256, 0, stream>>>(EBb, EKT, EKVT, Qb, out);
}

// Round 3
// 228.937 us; speedup vs baseline: 1.2509x; 1.0199x over previous
//
#include <hip/hip_runtime.h>

#define BSZ 8
#define SEQL 1024
#define CHN 1024
#define M1 (BSZ*SEQL)

typedef __attribute__((ext_vector_type(8))) short bf16x8;
typedef __attribute__((ext_vector_type(4))) float f32x4;
typedef __attribute__((ext_vector_type(4))) unsigned short us4;
typedef __attribute__((ext_vector_type(8))) unsigned short us8;

static __device__ __forceinline__ unsigned short f2bf(float f){
  unsigned int u = __float_as_uint(f);
  u += 0x7fffu + ((u >> 16) & 1u);
  return (unsigned short)(u >> 16);
}
static __device__ __forceinline__ float bf2f(unsigned short h){
  return __uint_as_float(((unsigned int)h) << 16);
}
static __device__ __forceinline__ void gload16(const void* g, void* l){
  __builtin_amdgcn_global_load_lds((const __attribute__((address_space(1))) void*)g,
                                   (__attribute__((address_space(3))) void*)l,
                                   16, 0, 0);
}
// 16B-chunk XOR swizzle within a 64B row of a [rows][32-short] staging tile.
static __device__ __forceinline__ int swzc(int row, int chunk){
  return chunk ^ ((row >> 1) & 3);
}

// ---------------- prep: fp32 -> bf16 conversions + exp(bias) ----------------
__global__ void prep_kernel(const float* __restrict__ x, const float* __restrict__ wq,
                            const float* __restrict__ wk, const float* __restrict__ wv,
                            const float* __restrict__ bias,
                            unsigned short* __restrict__ xb, unsigned short* __restrict__ wqb,
                            unsigned short* __restrict__ wkb, unsigned short* __restrict__ wvb,
                            unsigned short* __restrict__ ebb)
{
  const int NX = M1 * CHN;
  const int NW = CHN * CHN;
  const int total4 = (NX + 3 * NW + SEQL * SEQL) >> 2;
  for (int i = blockIdx.x * blockDim.x + threadIdx.x; i < total4;
       i += gridDim.x * blockDim.x) {
    int e = i << 2;
    const float* src; unsigned short* dst; int off; bool ex = false;
    if (e < NX)               { src = x;    dst = xb;  off = e; }
    else if (e < NX + NW)     { src = wq;   dst = wqb; off = e - NX; }
    else if (e < NX + 2 * NW) { src = wk;   dst = wkb; off = e - (NX + NW); }
    else if (e < NX + 3 * NW) { src = wv;   dst = wvb; off = e - (NX + 2 * NW); }
    else                      { src = bias; dst = ebb; off = e - (NX + 3 * NW); ex = true; }
    float4 v = *reinterpret_cast<const float4*>(src + off);
    if (ex) { v.x = expf(v.x); v.y = expf(v.y); v.z = expf(v.z); v.w = expf(v.w); }
    us4 o; o.x = f2bf(v.x); o.y = f2bf(v.y); o.z = f2bf(v.z); o.w = f2bf(v.w);
    *reinterpret_cast<us4*>(dst + off) = o;
  }
}

// ---------------- gemm_q: Q = X @ Wq^T + bq -> bf16 (m97-class 128x128) ----------------
__global__ __launch_bounds__(256) void gemm_q(
    const unsigned short* __restrict__ Xb, const unsigned short* __restrict__ Wq,
    const float* __restrict__ bq, unsigned short* __restrict__ Qb)
{
  __shared__ unsigned short lds[8192];   // A 128x32 | B 128x32 (16 KiB)
  const int tid = threadIdx.x;
  const int lane = tid & 63;
  const int wm = tid >> 7;
  const int wn = (tid >> 6) & 1;
  const int nwg = gridDim.x;             // 512
  const int lid = blockIdx.x;
  const int sid = (lid & 7) * (nwg >> 3) + (lid >> 3);
  // n fastest within an XCD chunk: A (X, the big operand) stays L2-resident.
  const int m0 = (sid >> 3) * 128;
  const int n0 = (sid & 7) * 128;

  const int linA0 = tid * 16, linA1 = 4096 + tid * 16;
  const int rA0 = linA0 >> 6, cA0 = (linA0 >> 4) & 3;
  const int rA1 = linA1 >> 6, cA1 = (linA1 >> 4) & 3;
  const unsigned short* gA0 = Xb + (m0 + rA0) * CHN + swzc(rA0, cA0) * 8;
  const unsigned short* gA1 = Xb + (m0 + rA1) * CHN + swzc(rA1, cA1) * 8;
  const unsigned short* gB0 = Wq + (n0 + rA0) * CHN + swzc(rA0, cA0) * 8;
  const unsigned short* gB1 = Wq + (n0 + rA1) * CHN + swzc(rA1, cA1) * 8;
  unsigned short* lA0 = lds + (linA0 >> 1);
  unsigned short* lA1 = lds + (linA1 >> 1);
  unsigned short* lB0 = lds + 4096 + (linA0 >> 1);
  unsigned short* lB1 = lds + 4096 + (linA1 >> 1);

  int aOff[4], bOff[4];
#pragma unroll
  for (int mi = 0; mi < 4; mi++) {
    int r = wm * 64 + mi * 16 + (lane & 15);
    aOff[mi] = r * 32 + swzc(r, lane >> 4) * 8;
  }
#pragma unroll
  for (int ni = 0; ni < 4; ni++) {
    int r = wn * 64 + ni * 16 + (lane & 15);
    bOff[ni] = 4096 + r * 32 + swzc(r, lane >> 4) * 8;
  }

  f32x4 acc[4][4] = {};
  for (int kk = 0; kk < CHN; kk += 32) {
    gload16(gA0 + kk, lA0); gload16(gA1 + kk, lA1);
    gload16(gB0 + kk, lB0); gload16(gB1 + kk, lB1);
    __syncthreads();
    bf16x8 af[4], bf[4];
#pragma unroll
    for (int mi = 0; mi < 4; mi++) af[mi] = *reinterpret_cast<const bf16x8*>(lds + aOff[mi]);
#pragma unroll
    for (int ni = 0; ni < 4; ni++) bf[ni] = *reinterpret_cast<const bf16x8*>(lds + bOff[ni]);
#pragma unroll
    for (int ni = 0; ni < 4; ni++)
#pragma unroll
      for (int mi = 0; mi < 4; mi++)
        acc[mi][ni] = __builtin_amdgcn_mfma_f32_16x16x32_bf16(af[mi], bf[ni], acc[mi][ni], 0, 0, 0);
    __syncthreads();
  }

  const int rb = (lane >> 4) * 4;
  float bqv[4];
#pragma unroll
  for (int ni = 0; ni < 4; ni++) bqv[ni] = bq[n0 + wn * 64 + ni * 16 + (lane & 15)];
#pragma unroll
  for (int mi = 0; mi < 4; mi++)
#pragma unroll
    for (int ni = 0; ni < 4; ni++)
#pragma unroll
      for (int r = 0; r < 4; r++) {
        int mrow = m0 + wm * 64 + mi * 16 + rb + r;
        int col  = n0 + wn * 64 + ni * 16 + (lane & 15);
        Qb[mrow * CHN + col] = f2bf(acc[mi][ni][r] + bqv[ni]);
      }
}

// ---------------- gemm_kv: k,v = X @ W{k,v}^T + b; write EKT/EKVT transposed ----------------
__global__ __launch_bounds__(256) void gemm_kv(
    const unsigned short* __restrict__ Xb,
    const unsigned short* __restrict__ Wk, const unsigned short* __restrict__ Wv,
    const float* __restrict__ bk, const float* __restrict__ bv,
    unsigned short* __restrict__ EKT, unsigned short* __restrict__ EKVT)
{
  __shared__ unsigned short lds[8704];   // staging 8192 shorts; transpose 64x136=8704
  const int tid = threadIdx.x;
  const int lane = tid & 63;
  const int wm = tid >> 7;
  const int wn = (tid >> 6) & 1;
  const int nwg = gridDim.x;             // 1024
  const int lid = blockIdx.x;
  const int sid = (lid & 7) * (nwg >> 3) + (lid >> 3);
  // n fastest within an XCD chunk: A (X) L2-resident, B panels stream via L3.
  const int m0 = (sid >> 4) * 128;
  const int n0 = (sid & 15) * 64;

  const int linA0 = tid * 16, linA1 = 4096 + tid * 16;
  const int rA0 = linA0 >> 6, cA0 = (linA0 >> 4) & 3;
  const int rA1 = linA1 >> 6, cA1 = (linA1 >> 4) & 3;
  const unsigned short* gA0 = Xb + (m0 + rA0) * CHN + swzc(rA0, cA0) * 8;
  const unsigned short* gA1 = Xb + (m0 + rA1) * CHN + swzc(rA1, cA1) * 8;
  const int rB = tid >> 2, cB = tid & 3;
  const unsigned short* gBk = Wk + (n0 + rB) * CHN + swzc(rB, cB) * 8;
  const unsigned short* gBv = Wv + (n0 + rB) * CHN + swzc(rB, cB) * 8;
  unsigned short* lA0 = lds + (linA0 >> 1);
  unsigned short* lA1 = lds + (linA1 >> 1);
  unsigned short* lBk = lds + 4096 + tid * 8;
  unsigned short* lBv = lds + 6144 + tid * 8;

  int aOff[4], bOff[2];
#pragma unroll
  for (int mi = 0; mi < 4; mi++) {
    int r = wm * 64 + mi * 16 + (lane & 15);
    aOff[mi] = r * 32 + swzc(r, lane >> 4) * 8;
  }
#pragma unroll
  for (int ni = 0; ni < 2; ni++) {
    int r = wn * 32 + ni * 16 + (lane & 15);
    bOff[ni] = r * 32 + swzc(r, lane >> 4) * 8;
  }

  f32x4 acck[4][2] = {}, accv[4][2] = {};
  for (int kk = 0; kk < CHN; kk += 32) {
    gload16(gA0 + kk, lA0); gload16(gA1 + kk, lA1);
    gload16(gBk + kk, lBk); gload16(gBv + kk, lBv);
    __syncthreads();
    bf16x8 af[4];
#pragma unroll
    for (int mi = 0; mi < 4; mi++) af[mi] = *reinterpret_cast<const bf16x8*>(lds + aOff[mi]);
#pragma unroll
    for (int ni = 0; ni < 2; ni++) {
      bf16x8 bk_ = *reinterpret_cast<const bf16x8*>(lds + 4096 + bOff[ni]);
      bf16x8 bv_ = *reinterpret_cast<const bf16x8*>(lds + 6144 + bOff[ni]);
#pragma unroll
      for (int mi = 0; mi < 4; mi++) {
        acck[mi][ni] = __builtin_amdgcn_mfma_f32_16x16x32_bf16(af[mi], bk_, acck[mi][ni], 0, 0, 0);
        accv[mi][ni] = __builtin_amdgcn_mfma_f32_16x16x32_bf16(af[mi], bv_, accv[mi][ni], 0, 0, 0);
      }
    }
    __syncthreads();
  }

  // ---- epilogue: ek = exp(k+bk), ekv = ek*(v+bv); transposed bf16 writes ----
  const int bIdx = m0 >> 10;
  const int s0 = m0 & 1023;
  const int rb = (lane >> 4) * 4;
  float bkv[2], bvv[2];
#pragma unroll
  for (int ni = 0; ni < 2; ni++) {
    int c = n0 + wn * 32 + ni * 16 + (lane & 15);
    bkv[ni] = bk[c]; bvv[ni] = bv[c];
  }
#pragma unroll
  for (int mi = 0; mi < 4; mi++)
#pragma unroll
    for (int ni = 0; ni < 2; ni++)
#pragma unroll
      for (int r = 0; r < 4; r++) {
        float ekf = expf(acck[mi][ni][r] + bkv[ni]);
        acck[mi][ni][r] = ekf;
        accv[mi][ni][r] = ekf * (accv[mi][ni][r] + bvv[ni]);
      }
  // pass 1: ek -> LDS transpose -> EKT
#pragma unroll
  for (int mi = 0; mi < 4; mi++)
#pragma unroll
    for (int ni = 0; ni < 2; ni++) {
      int nloc = wn * 32 + ni * 16 + (lane & 15);
#pragma unroll
      for (int r = 0; r < 4; r++)
        lds[nloc * 136 + wm * 64 + mi * 16 + rb + r] = f2bf(acck[mi][ni][r]);
    }
  __syncthreads();
#pragma unroll
  for (int it = 0; it < 4; it++) {
    int ch = it * 256 + tid;
    int nloc = ch >> 4, c8 = ch & 15;
    us8 v = *reinterpret_cast<const us8*>(lds + nloc * 136 + c8 * 8);
    *reinterpret_cast<us8*>(EKT + (bIdx * CHN + n0 + nloc) * SEQL + s0 + c8 * 8) = v;
  }
  __syncthreads();
  // pass 2: ekv -> LDS transpose -> EKVT
#pragma unroll
  for (int mi = 0; mi < 4; mi++)
#pragma unroll
    for (int ni = 0; ni < 2; ni++) {
      int nloc = wn * 32 + ni * 16 + (lane & 15);
#pragma unroll
      for (int r = 0; r < 4; r++)
        lds[nloc * 136 + wm * 64 + mi * 16 + rb + r] = f2bf(accv[mi][ni][r]);
    }
  __syncthreads();
#pragma unroll
  for (int it = 0; it < 4; it++) {
    int ch = it * 256 + tid;
    int nloc = ch >> 4, c8 = ch & 15;
    us8 v = *reinterpret_cast<const us8*>(lds + nloc * 136 + c8 * 8);
    *reinterpret_cast<us8*>(EKVT + (bIdx * CHN + n0 + nloc) * SEQL + s0 + c8 * 8) = v;
  }
}

// ---------------- gemm_aft: num/den = EB @ {EKVT,EKT}^T; out = sigmoid(q)*num/den ----------------
__global__ __launch_bounds__(256) void gemm_aft(
    const unsigned short* __restrict__ EB,
    const unsigned short* __restrict__ EKT, const unsigned short* __restrict__ EKVT,
    const unsigned short* __restrict__ Qb, float* __restrict__ out)
{
  __shared__ unsigned short lds[8192];   // A 128x32 | Bd 64x32 | Bn 64x32
  const int tid = threadIdx.x;
  const int lane = tid & 63;
  const int wm = tid >> 7;
  const int wn = (tid >> 6) & 1;
  const int nwg = gridDim.x;             // 1024
  const int lid = blockIdx.x;
  const int sid = (lid & 7) * (nwg >> 3) + (lid >> 3);
  const int t0 = (sid & 7) * 128;
  const int n0 = (sid >> 3) * 64;

  const int linA0 = tid * 16, linA1 = 4096 + tid * 16;
  const int rA0 = linA0 >> 6, cA0 = (linA0 >> 4) & 3;
  const int rA1 = linA1 >> 6, cA1 = (linA1 >> 4) & 3;
  const unsigned short* gA0 = EB + (t0 + rA0) * SEQL + swzc(rA0, cA0) * 8;
  const unsigned short* gA1 = EB + (t0 + rA1) * SEQL + swzc(rA1, cA1) * 8;
  const int rB = tid >> 2, cB = tid & 3;
  const unsigned short* gBd = EKT + (n0 + rB) * SEQL + swzc(rB, cB) * 8;
  const unsigned short* gBn = EKVT + (n0 + rB) * SEQL + swzc(rB, cB) * 8;
  unsigned short* lA0 = lds + (linA0 >> 1);
  unsigned short* lA1 = lds + (linA1 >> 1);
  unsigned short* lBd = lds + 4096 + tid * 8;
  unsigned short* lBn = lds + 6144 + tid * 8;

  int aOff[4], bOff[2];
#pragma unroll
  for (int mi = 0; mi < 4; mi++) {
    int r = wm * 64 + mi * 16 + (lane & 15);
    aOff[mi] = r * 32 + swzc(r, lane >> 4) * 8;
  }
#pragma unroll
  for (int ni = 0; ni < 2; ni++) {
    int r = wn * 32 + ni * 16 + (lane & 15);
    bOff[ni] = r * 32 + swzc(r, lane >> 4) * 8;
  }

  f32x4 accd[4][2] = {}, accn[4][2] = {};
  for (int kk = 0; kk < SEQL; kk += 32) {
    gload16(gA0 + kk, lA0); gload16(gA1 + kk, lA1);
    gload16(gBd + kk, lBd); gload16(gBn + kk, lBn);
    __syncthreads();
    bf16x8 af[4];
#pragma unroll
    for (int mi = 0; mi < 4; mi++) af[mi] = *reinterpret_cast<const bf16x8*>(lds + aOff[mi]);
#pragma unroll
    for (int ni = 0; ni < 2; ni++) {
      bf16x8 bd_ = *reinterpret_cast<const bf16x8*>(lds + 4096 + bOff[ni]);
      bf16x8 bn_ = *reinterpret_cast<const bf16x8*>(lds + 6144 + bOff[ni]);
#pragma unroll
      for (int mi = 0; mi < 4; mi++) {
        accd[mi][ni] = __builtin_amdgcn_mfma_f32_16x16x32_bf16(af[mi], bd_, accd[mi][ni], 0, 0, 0);
        accn[mi][ni] = __builtin_amdgcn_mfma_f32_16x16x32_bf16(af[mi], bn_, accn[mi][ni], 0, 0, 0);
      }
    }
    __syncthreads();
  }

  const int rb = (lane >> 4) * 4;
#pragma unroll
  for (int mi = 0; mi < 4; mi++)
#pragma unroll
    for (int ni = 0; ni < 2; ni++) {
      int nloc = wn * 32 + ni * 16 + (lane & 15);
      int n = n0 + nloc;
      int b = n >> 10, c = n & 1023;
#pragma unroll
      for (int r = 0; r < 4; r++) {
        int t = t0 + wm * 64 + mi * 16 + rb + r;
        float qv = bf2f(Qb[(b * SEQL + t) * CHN + c]);
        float sig = 1.0f / (1.0f + expf(-qv));
        out[(b * SEQL + t) * CHN + c] = sig * accn[mi][ni][r] / accd[mi][ni][r];
      }
    }
}

extern "C" void kernel_launch(void* const* d_in, const int* in_sizes, int n_in,
                              void* d_out, int out_size, void* d_ws, size_t ws_size,
                              hipStream_t stream) {
  (void)in_sizes; (void)n_in; (void)out_size; (void)ws_size;
  const float* x    = (const float*)d_in[0];
  const float* wq   = (const float*)d_in[1];
  const float* wk   = (const float*)d_in[2];
  const float* wv   = (const float*)d_in[3];
  const float* bq   = (const float*)d_in[4];
  const float* bk   = (const float*)d_in[5];
  const float* bv   = (const float*)d_in[6];
  const float* bias = (const float*)d_in[7];
  float* out = (float*)d_out;

  char* ws = (char*)d_ws;
  const size_t MB = 1024 * 1024;
  unsigned short* Xb   = (unsigned short*)(ws);
  unsigned short* Wqb  = (unsigned short*)(ws + 16 * MB);
  unsigned short* Wkb  = (unsigned short*)(ws + 18 * MB);
  unsigned short* Wvb  = (unsigned short*)(ws + 20 * MB);
  unsigned short* EBb  = (unsigned short*)(ws + 22 * MB);
  unsigned short* Qb   = (unsigned short*)(ws + 24 * MB);
  unsigned short* EKT  = (unsigned short*)(ws + 40 * MB);
  unsigned short* EKVT = (unsigned short*)(ws + 56 * MB);

  prep_kernel<<<2048, 256, 0, stream>>>(x, wq, wk, wv, bias, Xb, Wqb, Wkb, Wvb, EBb);
  gemm_q<<<512, 256, 0, stream>>>(Xb, Wqb, bq, Qb);
  gemm_kv<<<1024, 256, 0, stream>>>(Xb, Wkb, Wvb, bk, bv, EKT, EKVT);
  gemm_aft<<<1024, 256, 0, stream>>>(EBb, EKT, EKVT, Qb, out);
}

// Round 4
// 202.682 us; speedup vs baseline: 1.4130x; 1.1295x over previous
//
#include <hip/hip_runtime.h>

#define BSZ 8
#define SEQL 1024
#define CHN 1024
#define M1 (BSZ*SEQL)

typedef __attribute__((ext_vector_type(8))) short bf16x8;
typedef __attribute__((ext_vector_type(4))) float f32x4;
typedef __attribute__((ext_vector_type(4))) unsigned short us4;
typedef __attribute__((ext_vector_type(8))) unsigned short us8;

static __device__ __forceinline__ unsigned short f2bf(float f){
  unsigned int u = __float_as_uint(f);
  u += 0x7fffu + ((u >> 16) & 1u);
  return (unsigned short)(u >> 16);
}
static __device__ __forceinline__ float bf2f(unsigned short h){
  return __uint_as_float(((unsigned int)h) << 16);
}
static __device__ __forceinline__ void gload16(const void* g, void* l){
  __builtin_amdgcn_global_load_lds((const __attribute__((address_space(1))) void*)g,
                                   (__attribute__((address_space(3))) void*)l,
                                   16, 0, 0);
}

// ---------------- prep: fp32 -> bf16 conversions + exp(bias) ----------------
__global__ void prep_kernel(const float* __restrict__ x, const float* __restrict__ wq,
                            const float* __restrict__ wk, const float* __restrict__ wv,
                            const float* __restrict__ bias,
                            unsigned short* __restrict__ xb, unsigned short* __restrict__ wqb,
                            unsigned short* __restrict__ wkb, unsigned short* __restrict__ wvb,
                            unsigned short* __restrict__ ebb)
{
  const int NX = M1 * CHN;
  const int NW = CHN * CHN;
  const int total4 = (NX + 3 * NW + SEQL * SEQL) >> 2;
  for (int i = blockIdx.x * blockDim.x + threadIdx.x; i < total4;
       i += gridDim.x * blockDim.x) {
    int e = i << 2;
    const float* src; unsigned short* dst; int off; bool ex = false;
    if (e < NX)               { src = x;    dst = xb;  off = e; }
    else if (e < NX + NW)     { src = wq;   dst = wqb; off = e - NX; }
    else if (e < NX + 2 * NW) { src = wk;   dst = wkb; off = e - (NX + NW); }
    else if (e < NX + 3 * NW) { src = wv;   dst = wvb; off = e - (NX + 2 * NW); }
    else                      { src = bias; dst = ebb; off = e - (NX + 3 * NW); ex = true; }
    float4 v = *reinterpret_cast<const float4*>(src + off);
    if (ex) { v.x = expf(v.x); v.y = expf(v.y); v.z = expf(v.z); v.w = expf(v.w); }
    us4 o; o.x = f2bf(v.x); o.y = f2bf(v.y); o.z = f2bf(v.z); o.w = f2bf(v.w);
    *reinterpret_cast<us4*>(dst + off) = o;
  }
}

// ---------------- gemm_qkv: q,k,v = X @ W{q,k,v}^T + b  (BM=128,BN=64,BK=64) ----
// Epilogue: Qb[m][c] bf16; EKT[(b*C+c)][s]=exp(k), EKVT=exp(k)*v (transposed bf16).
// LDS swizzle: within a 64-short (128B) row of each staging tile, 16B chunk at
// physical slot pc holds logical chunk pc^(row&7); reads apply the same XOR.
__global__ __launch_bounds__(256) void gemm_qkv(
    const unsigned short* __restrict__ Xb,
    const unsigned short* __restrict__ Wq, const unsigned short* __restrict__ Wk,
    const unsigned short* __restrict__ Wv,
    const float* __restrict__ bq, const float* __restrict__ bk,
    const float* __restrict__ bv,
    unsigned short* __restrict__ Qb,
    unsigned short* __restrict__ EKT, unsigned short* __restrict__ EKVT)
{
  __shared__ unsigned short lds[20480];  // A[128][64] | Bq[64][64] | Bk | Bv = 40 KiB
  const int tid = threadIdx.x;
  const int lane = tid & 63;
  const int wm = tid >> 7;
  const int wn = (tid >> 6) & 1;
  const int nwg = gridDim.x;             // 1024
  const int lid = blockIdx.x;
  const int sid = (lid & 7) * (nwg >> 3) + (lid >> 3);
  const int m0 = (sid >> 4) * 128;       // n fastest in XCD chunk: X panel L2-resident
  const int n0 = (sid & 15) * 64;

  // staging descriptors (pre-swizzled global sources, linear LDS dests)
  const unsigned short* srcA[4]; unsigned short* dstA[4];
#pragma unroll
  for (int p = 0; p < 4; p++) {
    int l = p * 4096 + tid * 16;         // byte offset in 16 KiB A tile
    int row = l >> 7;
    int lc = ((l >> 4) & 7) ^ (row & 7);
    srcA[p] = Xb + (m0 + row) * CHN + lc * 8;
    dstA[p] = lds + (l >> 1);
  }
  const unsigned short* Ws0 = Wq; const unsigned short* Ws1 = Wk; const unsigned short* Ws2 = Wv;
  const unsigned short* srcB[3][2]; unsigned short* dstB[3][2];
#pragma unroll
  for (int w = 0; w < 3; w++) {
    const unsigned short* W = (w == 0) ? Ws0 : (w == 1) ? Ws1 : Ws2;
#pragma unroll
    for (int p = 0; p < 2; p++) {
      int l = p * 4096 + tid * 16;       // byte offset in 8 KiB B tile
      int row = l >> 7;
      int lc = ((l >> 4) & 7) ^ (row & 7);
      srcB[w][p] = W + (n0 + row) * CHN + lc * 8;
      dstB[w][p] = lds + 8192 + w * 4096 + (l >> 1);
    }
  }

  int aOff[4][2], bOff[2][2];
#pragma unroll
  for (int mi = 0; mi < 4; mi++) {
    int r = wm * 64 + mi * 16 + (lane & 15);
#pragma unroll
    for (int ks = 0; ks < 2; ks++)
      aOff[mi][ks] = r * 64 + ((((ks << 2) + (lane >> 4)) ^ (r & 7)) << 3);
  }
#pragma unroll
  for (int ni = 0; ni < 2; ni++) {
    int r = wn * 32 + ni * 16 + (lane & 15);
#pragma unroll
    for (int ks = 0; ks < 2; ks++)
      bOff[ni][ks] = r * 64 + ((((ks << 2) + (lane >> 4)) ^ (r & 7)) << 3);
  }

  f32x4 accq[4][2] = {}, acck[4][2] = {}, accv[4][2] = {};

  for (int kk = 0; kk < CHN; kk += 64) {
#pragma unroll
    for (int p = 0; p < 4; p++) gload16(srcA[p] + kk, dstA[p]);
#pragma unroll
    for (int w = 0; w < 3; w++)
#pragma unroll
      for (int p = 0; p < 2; p++) gload16(srcB[w][p] + kk, dstB[w][p]);
    __syncthreads();
#pragma unroll
    for (int ks = 0; ks < 2; ks++) {
      bf16x8 af[4];
#pragma unroll
      for (int mi = 0; mi < 4; mi++)
        af[mi] = *reinterpret_cast<const bf16x8*>(lds + aOff[mi][ks]);
#pragma unroll
      for (int ni = 0; ni < 2; ni++) {
        bf16x8 bq_ = *reinterpret_cast<const bf16x8*>(lds + 8192 + bOff[ni][ks]);
        bf16x8 bk_ = *reinterpret_cast<const bf16x8*>(lds + 12288 + bOff[ni][ks]);
        bf16x8 bv_ = *reinterpret_cast<const bf16x8*>(lds + 16384 + bOff[ni][ks]);
#pragma unroll
        for (int mi = 0; mi < 4; mi++) {
          accq[mi][ni] = __builtin_amdgcn_mfma_f32_16x16x32_bf16(af[mi], bq_, accq[mi][ni], 0, 0, 0);
          acck[mi][ni] = __builtin_amdgcn_mfma_f32_16x16x32_bf16(af[mi], bk_, acck[mi][ni], 0, 0, 0);
          accv[mi][ni] = __builtin_amdgcn_mfma_f32_16x16x32_bf16(af[mi], bv_, accv[mi][ni], 0, 0, 0);
        }
      }
    }
    __syncthreads();
  }

  // ---- epilogue ----
  const int bIdx = m0 >> 10;
  const int s0 = m0 & 1023;
  const int rb = (lane >> 4) * 4;
  float bqv[2], bkv[2], bvv[2];
#pragma unroll
  for (int ni = 0; ni < 2; ni++) {
    int c = n0 + wn * 32 + ni * 16 + (lane & 15);
    bqv[ni] = bq[c]; bkv[ni] = bk[c]; bvv[ni] = bv[c];
  }
  // Q write + exp transforms in-register
#pragma unroll
  for (int mi = 0; mi < 4; mi++)
#pragma unroll
    for (int ni = 0; ni < 2; ni++) {
      int col = n0 + wn * 32 + ni * 16 + (lane & 15);
#pragma unroll
      for (int r = 0; r < 4; r++) {
        int mrow = m0 + wm * 64 + mi * 16 + rb + r;
        Qb[mrow * CHN + col] = f2bf(accq[mi][ni][r] + bqv[ni]);
        float ekf = expf(acck[mi][ni][r] + bkv[ni]);
        acck[mi][ni][r] = ekf;
        accv[mi][ni][r] = ekf * (accv[mi][ni][r] + bvv[ni]);
      }
    }
  // pass 1: ek -> LDS transpose -> EKT   (all waves past final loop barrier)
#pragma unroll
  for (int mi = 0; mi < 4; mi++)
#pragma unroll
    for (int ni = 0; ni < 2; ni++) {
      int nloc = wn * 32 + ni * 16 + (lane & 15);
#pragma unroll
      for (int r = 0; r < 4; r++)
        lds[nloc * 136 + wm * 64 + mi * 16 + rb + r] = f2bf(acck[mi][ni][r]);
    }
  __syncthreads();
#pragma unroll
  for (int it = 0; it < 4; it++) {
    int ch = it * 256 + tid;
    int nloc = ch >> 4, c8 = ch & 15;
    us8 v = *reinterpret_cast<const us8*>(lds + nloc * 136 + c8 * 8);
    *reinterpret_cast<us8*>(EKT + (bIdx * CHN + n0 + nloc) * SEQL + s0 + c8 * 8) = v;
  }
  __syncthreads();
  // pass 2: ekv -> LDS transpose -> EKVT
#pragma unroll
  for (int mi = 0; mi < 4; mi++)
#pragma unroll
    for (int ni = 0; ni < 2; ni++) {
      int nloc = wn * 32 + ni * 16 + (lane & 15);
#pragma unroll
      for (int r = 0; r < 4; r++)
        lds[nloc * 136 + wm * 64 + mi * 16 + rb + r] = f2bf(accv[mi][ni][r]);
    }
  __syncthreads();
#pragma unroll
  for (int it = 0; it < 4; it++) {
    int ch = it * 256 + tid;
    int nloc = ch >> 4, c8 = ch & 15;
    us8 v = *reinterpret_cast<const us8*>(lds + nloc * 136 + c8 * 8);
    *reinterpret_cast<us8*>(EKVT + (bIdx * CHN + n0 + nloc) * SEQL + s0 + c8 * 8) = v;
  }
}

// ---------------- gemm_aft: num/den = EB @ {EKVT,EKT}^T; out = sigmoid(q)*num/den ----
// BM=128, BN=64, BK=64.
__global__ __launch_bounds__(256) void gemm_aft(
    const unsigned short* __restrict__ EB,
    const unsigned short* __restrict__ EKT, const unsigned short* __restrict__ EKVT,
    const unsigned short* __restrict__ Qb, float* __restrict__ out)
{
  __shared__ unsigned short lds[16384];  // A[128][64] | Bd[64][64] | Bn[64][64] = 32 KiB
  const int tid = threadIdx.x;
  const int lane = tid & 63;
  const int wm = tid >> 7;
  const int wn = (tid >> 6) & 1;
  const int nwg = gridDim.x;             // 1024
  const int lid = blockIdx.x;
  const int sid = (lid & 7) * (nwg >> 3) + (lid >> 3);
  const int t0 = (sid & 7) * 128;        // t fastest: B panels L2-resident, EB resident
  const int n0 = (sid >> 3) * 64;

  const unsigned short* srcA[4]; unsigned short* dstA[4];
#pragma unroll
  for (int p = 0; p < 4; p++) {
    int l = p * 4096 + tid * 16;
    int row = l >> 7;
    int lc = ((l >> 4) & 7) ^ (row & 7);
    srcA[p] = EB + (t0 + row) * SEQL + lc * 8;
    dstA[p] = lds + (l >> 1);
  }
  const unsigned short* srcB[2][2]; unsigned short* dstB[2][2];
#pragma unroll
  for (int w = 0; w < 2; w++) {
    const unsigned short* B = (w == 0) ? EKT : EKVT;
#pragma unroll
    for (int p = 0; p < 2; p++) {
      int l = p * 4096 + tid * 16;
      int row = l >> 7;
      int lc = ((l >> 4) & 7) ^ (row & 7);
      srcB[w][p] = B + (n0 + row) * SEQL + lc * 8;
      dstB[w][p] = lds + 8192 + w * 4096 + (l >> 1);
    }
  }

  int aOff[4][2], bOff[2][2];
#pragma unroll
  for (int mi = 0; mi < 4; mi++) {
    int r = wm * 64 + mi * 16 + (lane & 15);
#pragma unroll
    for (int ks = 0; ks < 2; ks++)
      aOff[mi][ks] = r * 64 + ((((ks << 2) + (lane >> 4)) ^ (r & 7)) << 3);
  }
#pragma unroll
  for (int ni = 0; ni < 2; ni++) {
    int r = wn * 32 + ni * 16 + (lane & 15);
#pragma unroll
    for (int ks = 0; ks < 2; ks++)
      bOff[ni][ks] = r * 64 + ((((ks << 2) + (lane >> 4)) ^ (r & 7)) << 3);
  }

  f32x4 accd[4][2] = {}, accn[4][2] = {};

  for (int kk = 0; kk < SEQL; kk += 64) {
#pragma unroll
    for (int p = 0; p < 4; p++) gload16(srcA[p] + kk, dstA[p]);
#pragma unroll
    for (int w = 0; w < 2; w++)
#pragma unroll
      for (int p = 0; p < 2; p++) gload16(srcB[w][p] + kk, dstB[w][p]);
    __syncthreads();
#pragma unroll
    for (int ks = 0; ks < 2; ks++) {
      bf16x8 af[4];
#pragma unroll
      for (int mi = 0; mi < 4; mi++)
        af[mi] = *reinterpret_cast<const bf16x8*>(lds + aOff[mi][ks]);
#pragma unroll
      for (int ni = 0; ni < 2; ni++) {
        bf16x8 bd_ = *reinterpret_cast<const bf16x8*>(lds + 8192 + bOff[ni][ks]);
        bf16x8 bn_ = *reinterpret_cast<const bf16x8*>(lds + 12288 + bOff[ni][ks]);
#pragma unroll
        for (int mi = 0; mi < 4; mi++) {
          accd[mi][ni] = __builtin_amdgcn_mfma_f32_16x16x32_bf16(af[mi], bd_, accd[mi][ni], 0, 0, 0);
          accn[mi][ni] = __builtin_amdgcn_mfma_f32_16x16x32_bf16(af[mi], bn_, accn[mi][ni], 0, 0, 0);
        }
      }
    }
    __syncthreads();
  }

  const int rb = (lane >> 4) * 4;
#pragma unroll
  for (int mi = 0; mi < 4; mi++)
#pragma unroll
    for (int ni = 0; ni < 2; ni++) {
      int nloc = wn * 32 + ni * 16 + (lane & 15);
      int n = n0 + nloc;
      int b = n >> 10, c = n & 1023;
#pragma unroll
      for (int r = 0; r < 4; r++) {
        int t = t0 + wm * 64 + mi * 16 + rb + r;
        float qv = bf2f(Qb[(b * SEQL + t) * CHN + c]);
        float sig = 1.0f / (1.0f + expf(-qv));
        out[(b * SEQL + t) * CHN + c] = sig * accn[mi][ni][r] / accd[mi][ni][r];
      }
    }
}

extern "C" void kernel_launch(void* const* d_in, const int* in_sizes, int n_in,
                              void* d_out, int out_size, void* d_ws, size_t ws_size,
                              hipStream_t stream) {
  (void)in_sizes; (void)n_in; (void)out_size; (void)ws_size;
  const float* x    = (const float*)d_in[0];
  const float* wq   = (const float*)d_in[1];
  const float* wk   = (const float*)d_in[2];
  const float* wv   = (const float*)d_in[3];
  const float* bq   = (const float*)d_in[4];
  const float* bk   = (const float*)d_in[5];
  const float* bv   = (const float*)d_in[6];
  const float* bias = (const float*)d_in[7];
  float* out = (float*)d_out;

  char* ws = (char*)d_ws;
  const size_t MB = 1024 * 1024;
  unsigned short* Xb   = (unsigned short*)(ws);
  unsigned short* Wqb  = (unsigned short*)(ws + 16 * MB);
  unsigned short* Wkb  = (unsigned short*)(ws + 18 * MB);
  unsigned short* Wvb  = (unsigned short*)(ws + 20 * MB);
  unsigned short* EBb  = (unsigned short*)(ws + 22 * MB);
  unsigned short* Qb   = (unsigned short*)(ws + 24 * MB);
  unsigned short* EKT  = (unsigned short*)(ws + 40 * MB);
  unsigned short* EKVT = (unsigned short*)(ws + 56 * MB);

  prep_kernel<<<2048, 256, 0, stream>>>(x, wq, wk, wv, bias, Xb, Wqb, Wkb, Wvb, EBb);
  gemm_qkv<<<1024, 256, 0, stream>>>(Xb, Wqb, Wkb, Wvb, bq, bk, bv, Qb, EKT, EKVT);
  gemm_aft<<<1024, 256, 0, stream>>>(EBb, EKT, EKVT, Qb, out);
}

// Round 6
// 194.668 us; speedup vs baseline: 1.4711x; 1.0412x over previous
//
#include <hip/hip_runtime.h>

#define BSZ 8
#define SEQL 1024
#define CHN 1024
#define M1 (BSZ*SEQL)

typedef __attribute__((ext_vector_type(8))) short bf16x8;
typedef __attribute__((ext_vector_type(4))) float f32x4;
typedef __attribute__((ext_vector_type(4))) unsigned short us4;
typedef __attribute__((ext_vector_type(8))) unsigned short us8;

static __device__ __forceinline__ unsigned short f2bf(float f){
  unsigned int u = __float_as_uint(f);
  u += 0x7fffu + ((u >> 16) & 1u);
  return (unsigned short)(u >> 16);
}
static __device__ __forceinline__ float bf2f(unsigned short h){
  return __uint_as_float(((unsigned int)h) << 16);
}
static __device__ __forceinline__ void gload16(const void* g, void* l){
  __builtin_amdgcn_global_load_lds((const __attribute__((address_space(1))) void*)g,
                                   (__attribute__((address_space(3))) void*)l,
                                   16, 0, 0);
}

// raw barrier (no implicit vmcnt drain) with scheduling pins
#define SBAR() do { __builtin_amdgcn_sched_barrier(0); __builtin_amdgcn_s_barrier(); __builtin_amdgcn_sched_barrier(0); } while (0)
#define LGKM0() asm volatile("s_waitcnt lgkmcnt(0)" ::: "memory")
#define PRIO_HI() do { __builtin_amdgcn_s_setprio(1); __builtin_amdgcn_sched_barrier(0); } while (0)
#define PRIO_LO() do { __builtin_amdgcn_sched_barrier(0); __builtin_amdgcn_s_setprio(0); } while (0)

// ---------------- prep: fp32 -> bf16 conversions + exp(bias) ----------------
__global__ void prep_kernel(const float* __restrict__ x, const float* __restrict__ wq,
                            const float* __restrict__ wk, const float* __restrict__ wv,
                            const float* __restrict__ bias,
                            unsigned short* __restrict__ xb, unsigned short* __restrict__ wqb,
                            unsigned short* __restrict__ wkb, unsigned short* __restrict__ wvb,
                            unsigned short* __restrict__ ebb)
{
  const int NX = M1 * CHN;
  const int NW = CHN * CHN;
  const int total4 = (NX + 3 * NW + SEQL * SEQL) >> 2;
  for (int i = blockIdx.x * blockDim.x + threadIdx.x; i < total4;
       i += gridDim.x * blockDim.x) {
    int e = i << 2;
    const float* src; unsigned short* dst; int off; bool ex = false;
    if (e < NX)               { src = x;    dst = xb;  off = e; }
    else if (e < NX + NW)     { src = wq;   dst = wqb; off = e - NX; }
    else if (e < NX + 2 * NW) { src = wk;   dst = wkb; off = e - (NX + NW); }
    else if (e < NX + 3 * NW) { src = wv;   dst = wvb; off = e - (NX + 2 * NW); }
    else                      { src = bias; dst = ebb; off = e - (NX + 3 * NW); ex = true; }
    float4 v = *reinterpret_cast<const float4*>(src + off);
    if (ex) { v.x = expf(v.x); v.y = expf(v.y); v.z = expf(v.z); v.w = expf(v.w); }
    us4 o; o.x = f2bf(v.x); o.y = f2bf(v.y); o.z = f2bf(v.z); o.w = f2bf(v.w);
    *reinterpret_cast<us4*>(dst + off) = o;
  }
}

// ---------------- gemm_qkv: pipelined (counted-vmcnt, readiness-barrier fixed) ----
// 512 threads (8 waves, 4M x 2N), BM=128, BN=64 per W (3 Ws), BK=64, dbuf LDS.
__global__ __launch_bounds__(512, 2) void gemm_qkv(
    const unsigned short* __restrict__ Xb,
    const unsigned short* __restrict__ Wq, const unsigned short* __restrict__ Wk,
    const unsigned short* __restrict__ Wv,
    const float* __restrict__ bq, const float* __restrict__ bk,
    const float* __restrict__ bv,
    unsigned short* __restrict__ Qb,
    unsigned short* __restrict__ EKT, unsigned short* __restrict__ EKVT)
{
  __shared__ unsigned short lds[2 * 20480];  // per buf: A 8192 | Bq 4096 | Bk | Bv (40 KiB)
  const int tid = threadIdx.x;
  const int lane = tid & 63;
  const int wid = tid >> 6;
  const int wm = wid >> 1;               // 0..3 (32-row strip)
  const int wn = wid & 1;                // 0..1 (32-col strip)
  const int nwg = gridDim.x;             // 1024
  const int lid = blockIdx.x;
  const int sid = (lid & 7) * (nwg >> 3) + (lid >> 3);
  const int m0 = (sid >> 4) * 128;       // n fastest in XCD chunk
  const int n0 = (sid & 15) * 64;

  const unsigned short* srcA[2]; int dA[2];
#pragma unroll
  for (int p = 0; p < 2; p++) {
    int l = p * 8192 + tid * 16;
    int row = l >> 7;
    int lc = ((l >> 4) & 7) ^ (row & 7);
    srcA[p] = Xb + (m0 + row) * CHN + lc * 8;
    dA[p] = l >> 1;
  }
  const unsigned short* srcB[3]; int dB[3];
  {
    int l = tid * 16;
    int row = l >> 7;
    int lc = ((l >> 4) & 7) ^ (row & 7);
#pragma unroll
    for (int w = 0; w < 3; w++) {
      const unsigned short* W = (w == 0) ? Wq : (w == 1) ? Wk : Wv;
      srcB[w] = W + (n0 + row) * CHN + lc * 8;
      dB[w] = 8192 + w * 4096 + (l >> 1);
    }
  }

  int aOff[2][2], bOff[2][2];
#pragma unroll
  for (int mi = 0; mi < 2; mi++) {
    int r = wm * 32 + mi * 16 + (lane & 15);
#pragma unroll
    for (int ks = 0; ks < 2; ks++)
      aOff[mi][ks] = r * 64 + ((((ks << 2) + (lane >> 4)) ^ (r & 7)) << 3);
  }
#pragma unroll
  for (int ni = 0; ni < 2; ni++) {
    int r = wn * 32 + ni * 16 + (lane & 15);
#pragma unroll
    for (int ks = 0; ks < 2; ks++)
      bOff[ni][ks] = r * 64 + ((((ks << 2) + (lane >> 4)) ^ (r & 7)) << 3);
  }

  f32x4 accq[2][2] = {}, acck[2][2] = {}, accv[2][2] = {};

  // prologue: stage K-tile 0 into buf0
#pragma unroll
  for (int p = 0; p < 2; p++) gload16(srcA[p], lds + dA[p]);
#pragma unroll
  for (int w = 0; w < 3; w++) gload16(srcB[w], lds + dB[w]);

  for (int t = 0; t < 16; ++t) {
    const int cur = (t & 1) * 20480;
    const int nxt = 20480 - cur;
    const int kn = (t + 1) << 6;
    if (t < 15) {
#pragma unroll
      for (int p = 0; p < 2; p++) gload16(srcA[p] + kn, lds + nxt + dA[p]);
      // own loads for tile t landed; only A(t+1) (2 loads) may remain in flight
      asm volatile("s_waitcnt vmcnt(2)" ::: "memory");
    } else {
      asm volatile("s_waitcnt vmcnt(0)" ::: "memory");
    }
    SBAR();   // readiness: ALL waves' tile-t staging now resident in LDS
#pragma unroll
    for (int ks = 0; ks < 2; ks++) {
      bf16x8 af[2], bqf[2], bkf[2], bvf[2];
#pragma unroll
      for (int mi = 0; mi < 2; mi++)
        af[mi] = *reinterpret_cast<const bf16x8*>(lds + cur + aOff[mi][ks]);
#pragma unroll
      for (int ni = 0; ni < 2; ni++) {
        bqf[ni] = *reinterpret_cast<const bf16x8*>(lds + cur + 8192  + bOff[ni][ks]);
        bkf[ni] = *reinterpret_cast<const bf16x8*>(lds + cur + 12288 + bOff[ni][ks]);
        bvf[ni] = *reinterpret_cast<const bf16x8*>(lds + cur + 16384 + bOff[ni][ks]);
      }
      PRIO_HI();
#pragma unroll
      for (int ni = 0; ni < 2; ni++)
#pragma unroll
        for (int mi = 0; mi < 2; mi++) {
          accq[mi][ni] = __builtin_amdgcn_mfma_f32_16x16x32_bf16(af[mi], bqf[ni], accq[mi][ni], 0, 0, 0);
          acck[mi][ni] = __builtin_amdgcn_mfma_f32_16x16x32_bf16(af[mi], bkf[ni], acck[mi][ni], 0, 0, 0);
          accv[mi][ni] = __builtin_amdgcn_mfma_f32_16x16x32_bf16(af[mi], bvf[ni], accv[mi][ni], 0, 0, 0);
        }
      PRIO_LO();
      if (ks == 0 && t < 15) {
        // B(t+1) into nxt: nxt's last readers all passed the previous end-of-iter SBAR
#pragma unroll
        for (int w = 0; w < 3; w++) gload16(srcB[w] + kn, lds + nxt + dB[w]);
      }
    }
    LGKM0();
    SBAR();   // end-of-iter: all waves' reads of cur complete before next iter writes it
  }

  // ---- epilogue ----
  const int bIdx = m0 >> 10;
  const int s0 = m0 & 1023;
  const int rbq = (lane >> 4) * 4;
  float bqv[2], bkv[2], bvv[2];
#pragma unroll
  for (int ni = 0; ni < 2; ni++) {
    int c = n0 + wn * 32 + ni * 16 + (lane & 15);
    bqv[ni] = bq[c]; bkv[ni] = bk[c]; bvv[ni] = bv[c];
  }
#pragma unroll
  for (int mi = 0; mi < 2; mi++)
#pragma unroll
    for (int ni = 0; ni < 2; ni++) {
      int col = n0 + wn * 32 + ni * 16 + (lane & 15);
#pragma unroll
      for (int r = 0; r < 4; r++) {
        int mrow = m0 + wm * 32 + mi * 16 + rbq + r;
        Qb[mrow * CHN + col] = f2bf(accq[mi][ni][r] + bqv[ni]);
        float ekf = expf(acck[mi][ni][r] + bkv[ni]);
        acck[mi][ni][r] = ekf;
        accv[mi][ni][r] = ekf * (accv[mi][ni][r] + bvv[ni]);
      }
    }
  // pass 1: ek -> LDS transpose -> EKT
#pragma unroll
  for (int mi = 0; mi < 2; mi++)
#pragma unroll
    for (int ni = 0; ni < 2; ni++) {
      int nloc = wn * 32 + ni * 16 + (lane & 15);
#pragma unroll
      for (int r = 0; r < 4; r++)
        lds[nloc * 136 + wm * 32 + mi * 16 + rbq + r] = f2bf(acck[mi][ni][r]);
    }
  __syncthreads();
#pragma unroll
  for (int it = 0; it < 2; it++) {
    int ch = it * 512 + tid;
    int nloc = ch >> 4, c8 = ch & 15;
    us8 v = *reinterpret_cast<const us8*>(lds + nloc * 136 + c8 * 8);
    *reinterpret_cast<us8*>(EKT + (bIdx * CHN + n0 + nloc) * SEQL + s0 + c8 * 8) = v;
  }
  __syncthreads();
  // pass 2: ekv -> LDS transpose -> EKVT
#pragma unroll
  for (int mi = 0; mi < 2; mi++)
#pragma unroll
    for (int ni = 0; ni < 2; ni++) {
      int nloc = wn * 32 + ni * 16 + (lane & 15);
#pragma unroll
      for (int r = 0; r < 4; r++)
        lds[nloc * 136 + wm * 32 + mi * 16 + rbq + r] = f2bf(accv[mi][ni][r]);
    }
  __syncthreads();
#pragma unroll
  for (int it = 0; it < 2; it++) {
    int ch = it * 512 + tid;
    int nloc = ch >> 4, c8 = ch & 15;
    us8 v = *reinterpret_cast<const us8*>(lds + nloc * 136 + c8 * 8);
    *reinterpret_cast<us8*>(EKVT + (bIdx * CHN + n0 + nloc) * SEQL + s0 + c8 * 8) = v;
  }
}

// ---------------- gemm_aft: pipelined num/den GEMM + fused epilogue ----------------
__global__ __launch_bounds__(512, 4) void gemm_aft(
    const unsigned short* __restrict__ EB,
    const unsigned short* __restrict__ EKT, const unsigned short* __restrict__ EKVT,
    const unsigned short* __restrict__ Qb, float* __restrict__ out)
{
  __shared__ unsigned short lds[2 * 16384];  // per buf: A 8192 | Bd 4096 | Bn 4096
  const int tid = threadIdx.x;
  const int lane = tid & 63;
  const int wid = tid >> 6;
  const int wm = wid >> 1;
  const int wn = wid & 1;
  const int nwg = gridDim.x;             // 1024
  const int lid = blockIdx.x;
  const int sid = (lid & 7) * (nwg >> 3) + (lid >> 3);
  const int t0 = (sid & 7) * 128;        // t fastest: B panels L2-resident
  const int n0 = (sid >> 3) * 64;

  const unsigned short* srcA[2]; int dA[2];
#pragma unroll
  for (int p = 0; p < 2; p++) {
    int l = p * 8192 + tid * 16;
    int row = l >> 7;
    int lc = ((l >> 4) & 7) ^ (row & 7);
    srcA[p] = EB + (t0 + row) * SEQL + lc * 8;
    dA[p] = l >> 1;
  }
  const unsigned short* srcB[2]; int dB[2];
  {
    int l = tid * 16;
    int row = l >> 7;
    int lc = ((l >> 4) & 7) ^ (row & 7);
#pragma unroll
    for (int w = 0; w < 2; w++) {
      const unsigned short* B = (w == 0) ? EKT : EKVT;
      srcB[w] = B + (n0 + row) * SEQL + lc * 8;
      dB[w] = 8192 + w * 4096 + (l >> 1);
    }
  }

  int aOff[2][2], bOff[2][2];
#pragma unroll
  for (int mi = 0; mi < 2; mi++) {
    int r = wm * 32 + mi * 16 + (lane & 15);
#pragma unroll
    for (int ks = 0; ks < 2; ks++)
      aOff[mi][ks] = r * 64 + ((((ks << 2) + (lane >> 4)) ^ (r & 7)) << 3);
  }
#pragma unroll
  for (int ni = 0; ni < 2; ni++) {
    int r = wn * 32 + ni * 16 + (lane & 15);
#pragma unroll
    for (int ks = 0; ks < 2; ks++)
      bOff[ni][ks] = r * 64 + ((((ks << 2) + (lane >> 4)) ^ (r & 7)) << 3);
  }

  f32x4 accd[2][2] = {}, accn[2][2] = {};

#pragma unroll
  for (int p = 0; p < 2; p++) gload16(srcA[p], lds + dA[p]);
#pragma unroll
  for (int w = 0; w < 2; w++) gload16(srcB[w], lds + dB[w]);

  for (int t = 0; t < 16; ++t) {
    const int cur = (t & 1) * 16384;
    const int nxt = 16384 - cur;
    const int kn = (t + 1) << 6;
    if (t < 15) {
#pragma unroll
      for (int p = 0; p < 2; p++) gload16(srcA[p] + kn, lds + nxt + dA[p]);
      asm volatile("s_waitcnt vmcnt(2)" ::: "memory");
    } else {
      asm volatile("s_waitcnt vmcnt(0)" ::: "memory");
    }
    SBAR();   // readiness: ALL waves' tile-t staging resident
#pragma unroll
    for (int ks = 0; ks < 2; ks++) {
      bf16x8 af[2], bdf[2], bnf[2];
#pragma unroll
      for (int mi = 0; mi < 2; mi++)
        af[mi] = *reinterpret_cast<const bf16x8*>(lds + cur + aOff[mi][ks]);
#pragma unroll
      for (int ni = 0; ni < 2; ni++) {
        bdf[ni] = *reinterpret_cast<const bf16x8*>(lds + cur + 8192  + bOff[ni][ks]);
        bnf[ni] = *reinterpret_cast<const bf16x8*>(lds + cur + 12288 + bOff[ni][ks]);
      }
      PRIO_HI();
#pragma unroll
      for (int ni = 0; ni < 2; ni++)
#pragma unroll
        for (int mi = 0; mi < 2; mi++) {
          accd[mi][ni] = __builtin_amdgcn_mfma_f32_16x16x32_bf16(af[mi], bdf[ni], accd[mi][ni], 0, 0, 0);
          accn[mi][ni] = __builtin_amdgcn_mfma_f32_16x16x32_bf16(af[mi], bnf[ni], accn[mi][ni], 0, 0, 0);
        }
      PRIO_LO();
      if (ks == 0 && t < 15) {
#pragma unroll
        for (int w = 0; w < 2; w++) gload16(srcB[w] + kn, lds + nxt + dB[w]);
      }
    }
    LGKM0();
    SBAR();   // end-of-iter
  }

  const int rbq = (lane >> 4) * 4;
#pragma unroll
  for (int mi = 0; mi < 2; mi++)
#pragma unroll
    for (int ni = 0; ni < 2; ni++) {
      int nloc = wn * 32 + ni * 16 + (lane & 15);
      int n = n0 + nloc;
      int b = n >> 10, c = n & 1023;
#pragma unroll
      for (int r = 0; r < 4; r++) {
        int t = t0 + wm * 32 + mi * 16 + rbq + r;
        float qv = bf2f(Qb[(b * SEQL + t) * CHN + c]);
        float sig = 1.0f / (1.0f + expf(-qv));
        out[(b * SEQL + t) * CHN + c] = sig * accn[mi][ni][r] / accd[mi][ni][r];
      }
    }
}

extern "C" void kernel_launch(void* const* d_in, const int* in_sizes, int n_in,
                              void* d_out, int out_size, void* d_ws, size_t ws_size,
                              hipStream_t stream) {
  (void)in_sizes; (void)n_in; (void)out_size; (void)ws_size;
  const float* x    = (const float*)d_in[0];
  const float* wq   = (const float*)d_in[1];
  const float* wk   = (const float*)d_in[2];
  const float* wv   = (const float*)d_in[3];
  const float* bq   = (const float*)d_in[4];
  const float* bk   = (const float*)d_in[5];
  const float* bv   = (const float*)d_in[6];
  const float* bias = (const float*)d_in[7];
  float* out = (float*)d_out;

  char* ws = (char*)d_ws;
  const size_t MB = 1024 * 1024;
  unsigned short* Xb   = (unsigned short*)(ws);
  unsigned short* Wqb  = (unsigned short*)(ws + 16 * MB);
  unsigned short* Wkb  = (unsigned short*)(ws + 18 * MB);
  unsigned short* Wvb  = (unsigned short*)(ws + 20 * MB);
  unsigned short* EBb  = (unsigned short*)(ws + 22 * MB);
  unsigned short* Qb   = (unsigned short*)(ws + 24 * MB);
  unsigned short* EKT  = (unsigned short*)(ws + 40 * MB);
  unsigned short* EKVT = (unsigned short*)(ws + 56 * MB);

  prep_kernel<<<2048, 256, 0, stream>>>(x, wq, wk, wv, bias, Xb, Wqb, Wkb, Wvb, EBb);
  gemm_qkv<<<1024, 512, 0, stream>>>(Xb, Wqb, Wkb, Wvb, bq, bk, bv, Qb, EKT, EKVT);
  gemm_aft<<<1024, 512, 0, stream>>>(EBb, EKT, EKVT, Qb, out);
}

// Round 7
// 189.873 us; speedup vs baseline: 1.5083x; 1.0253x over previous
//
#include <hip/hip_runtime.h>

#define BSZ 8
#define SEQL 1024
#define CHN 1024
#define M1 (BSZ*SEQL)

typedef __attribute__((ext_vector_type(8))) short bf16x8;
typedef __attribute__((ext_vector_type(4))) float f32x4;
typedef __attribute__((ext_vector_type(4))) unsigned short us4;
typedef __attribute__((ext_vector_type(8))) unsigned short us8;

static __device__ __forceinline__ unsigned short f2bf(float f){
  unsigned int u = __float_as_uint(f);
  u += 0x7fffu + ((u >> 16) & 1u);
  return (unsigned short)(u >> 16);
}
static __device__ __forceinline__ float bf2f(unsigned short h){
  return __uint_as_float(((unsigned int)h) << 16);
}
static __device__ __forceinline__ void gload16(const void* g, void* l){
  __builtin_amdgcn_global_load_lds((const __attribute__((address_space(1))) void*)g,
                                   (__attribute__((address_space(3))) void*)l,
                                   16, 0, 0);
}

#define SBAR() do { __builtin_amdgcn_sched_barrier(0); __builtin_amdgcn_s_barrier(); __builtin_amdgcn_sched_barrier(0); } while (0)
#define LGKM0() asm volatile("s_waitcnt lgkmcnt(0)" ::: "memory")
#define PRIO_HI() do { __builtin_amdgcn_s_setprio(1); __builtin_amdgcn_sched_barrier(0); } while (0)
#define PRIO_LO() do { __builtin_amdgcn_sched_barrier(0); __builtin_amdgcn_s_setprio(0); } while (0)

// ---------------- prep: fp32 -> bf16 conversions + exp(bias) ----------------
__global__ void prep_kernel(const float* __restrict__ x, const float* __restrict__ wq,
                            const float* __restrict__ wk, const float* __restrict__ wv,
                            const float* __restrict__ bias,
                            unsigned short* __restrict__ xb, unsigned short* __restrict__ wqb,
                            unsigned short* __restrict__ wkb, unsigned short* __restrict__ wvb,
                            unsigned short* __restrict__ ebb)
{
  const int NX = M1 * CHN;
  const int NW = CHN * CHN;
  const int total4 = (NX + 3 * NW + SEQL * SEQL) >> 2;
  for (int i = blockIdx.x * blockDim.x + threadIdx.x; i < total4;
       i += gridDim.x * blockDim.x) {
    int e = i << 2;
    const float* src; unsigned short* dst; int off; bool ex = false;
    if (e < NX)               { src = x;    dst = xb;  off = e; }
    else if (e < NX + NW)     { src = wq;   dst = wqb; off = e - NX; }
    else if (e < NX + 2 * NW) { src = wk;   dst = wkb; off = e - (NX + NW); }
    else if (e < NX + 3 * NW) { src = wv;   dst = wvb; off = e - (NX + 2 * NW); }
    else                      { src = bias; dst = ebb; off = e - (NX + 3 * NW); ex = true; }
    float4 v = *reinterpret_cast<const float4*>(src + off);
    if (ex) { v.x = expf(v.x); v.y = expf(v.y); v.z = expf(v.z); v.w = expf(v.w); }
    us4 o; o.x = f2bf(v.x); o.y = f2bf(v.y); o.z = f2bf(v.z); o.w = f2bf(v.w);
    *reinterpret_cast<us4*>(dst + off) = o;
  }
}

// ---------------- gemm_qkv: BM=256, BN=64x3, BK=64, 8 waves (4M x 2N) --------
// Wave tile 64x(32x3): 38.4 FLOP/LDS-byte. R6-proven counted-vmcnt pipeline.
__global__ __launch_bounds__(512, 2) void gemm_qkv(
    const unsigned short* __restrict__ Xb,
    const unsigned short* __restrict__ Wq, const unsigned short* __restrict__ Wk,
    const unsigned short* __restrict__ Wv,
    const float* __restrict__ bq, const float* __restrict__ bk,
    const float* __restrict__ bv,
    unsigned short* __restrict__ Qb,
    unsigned short* __restrict__ EKT, unsigned short* __restrict__ EKVT)
{
  __shared__ unsigned short lds[2 * 28672];  // per buf: A 256x64 (32K) | Bq|Bk|Bv 64x64 (8K each)
  const int tid = threadIdx.x;
  const int lane = tid & 63;
  const int wid = tid >> 6;
  const int wm = wid >> 1;               // 0..3 -> 64-row strip
  const int wn = wid & 1;                // 0..1 -> 32-col strip per mat
  const int nwg = gridDim.x;             // 512
  const int lid = blockIdx.x;
  const int sid = (lid & 7) * (nwg >> 3) + (lid >> 3);
  const int m0 = (sid >> 4) * 256;       // n fastest in XCD chunk
  const int n0 = (sid & 15) * 64;

  const unsigned short* srcA[4]; int dA[4];
#pragma unroll
  for (int p = 0; p < 4; p++) {
    int l = p * 8192 + tid * 16;
    int row = l >> 7;
    int lc = ((l >> 4) & 7) ^ (row & 7);
    srcA[p] = Xb + (m0 + row) * CHN + lc * 8;
    dA[p] = l >> 1;
  }
  const unsigned short* srcB[3]; int dB[3];
  {
    int l = tid * 16;
    int row = l >> 7;
    int lc = ((l >> 4) & 7) ^ (row & 7);
#pragma unroll
    for (int w = 0; w < 3; w++) {
      const unsigned short* W = (w == 0) ? Wq : (w == 1) ? Wk : Wv;
      srcB[w] = W + (n0 + row) * CHN + lc * 8;
      dB[w] = 16384 + w * 4096 + (l >> 1);
    }
  }

  int aOff[4][2], bOff[2][2];
#pragma unroll
  for (int mi = 0; mi < 4; mi++) {
    int r = wm * 64 + mi * 16 + (lane & 15);
#pragma unroll
    for (int ks = 0; ks < 2; ks++)
      aOff[mi][ks] = r * 64 + ((((ks << 2) + (lane >> 4)) ^ (r & 7)) << 3);
  }
#pragma unroll
  for (int ni = 0; ni < 2; ni++) {
    int r = wn * 32 + ni * 16 + (lane & 15);
#pragma unroll
    for (int ks = 0; ks < 2; ks++)
      bOff[ni][ks] = r * 64 + ((((ks << 2) + (lane >> 4)) ^ (r & 7)) << 3);
  }

  f32x4 accq[4][2] = {}, acck[4][2] = {}, accv[4][2] = {};

#pragma unroll
  for (int p = 0; p < 4; p++) gload16(srcA[p], lds + dA[p]);
#pragma unroll
  for (int w = 0; w < 3; w++) gload16(srcB[w], lds + dB[w]);

  for (int t = 0; t < 16; ++t) {
    const int cur = (t & 1) * 28672;
    const int nxt = 28672 - cur;
    const int kn = (t + 1) << 6;
    if (t < 15) {
#pragma unroll
      for (int p = 0; p < 4; p++) gload16(srcA[p] + kn, lds + nxt + dA[p]);
      // FIFO: [A(t) x4, B(t) x3, A(t+1) x4] -> keep 4 newest
      asm volatile("s_waitcnt vmcnt(4)" ::: "memory");
    } else {
      asm volatile("s_waitcnt vmcnt(0)" ::: "memory");
    }
    SBAR();   // all waves' tile-t staging resident
#pragma unroll
    for (int ks = 0; ks < 2; ks++) {
      bf16x8 bqf[2], bkf[2], bvf[2];
#pragma unroll
      for (int ni = 0; ni < 2; ni++) {
        bqf[ni] = *reinterpret_cast<const bf16x8*>(lds + cur + 16384 + bOff[ni][ks]);
        bkf[ni] = *reinterpret_cast<const bf16x8*>(lds + cur + 20480 + bOff[ni][ks]);
        bvf[ni] = *reinterpret_cast<const bf16x8*>(lds + cur + 24576 + bOff[ni][ks]);
      }
      PRIO_HI();
#pragma unroll
      for (int mi = 0; mi < 4; mi++) {
        bf16x8 af = *reinterpret_cast<const bf16x8*>(lds + cur + aOff[mi][ks]);
#pragma unroll
        for (int ni = 0; ni < 2; ni++) {
          accq[mi][ni] = __builtin_amdgcn_mfma_f32_16x16x32_bf16(af, bqf[ni], accq[mi][ni], 0, 0, 0);
          acck[mi][ni] = __builtin_amdgcn_mfma_f32_16x16x32_bf16(af, bkf[ni], acck[mi][ni], 0, 0, 0);
          accv[mi][ni] = __builtin_amdgcn_mfma_f32_16x16x32_bf16(af, bvf[ni], accv[mi][ni], 0, 0, 0);
        }
      }
      PRIO_LO();
      if (ks == 0 && t < 15) {
#pragma unroll
        for (int w = 0; w < 3; w++) gload16(srcB[w] + kn, lds + nxt + dB[w]);
      }
    }
    LGKM0();
    SBAR();   // all reads of cur done before next iter overwrites it
  }

  // ---- epilogue ----
  const int bIdx = m0 >> 10;
  const int s0 = m0 & 1023;
  const int rbq = (lane >> 4) * 4;
  float bqv[2], bkv[2], bvv[2];
#pragma unroll
  for (int ni = 0; ni < 2; ni++) {
    int c = n0 + wn * 32 + ni * 16 + (lane & 15);
    bqv[ni] = bq[c]; bkv[ni] = bk[c]; bvv[ni] = bv[c];
  }
#pragma unroll
  for (int mi = 0; mi < 4; mi++)
#pragma unroll
    for (int ni = 0; ni < 2; ni++) {
      int col = n0 + wn * 32 + ni * 16 + (lane & 15);
#pragma unroll
      for (int r = 0; r < 4; r++) {
        int mrow = m0 + wm * 64 + mi * 16 + rbq + r;
        Qb[mrow * CHN + col] = f2bf(accq[mi][ni][r] + bqv[ni]);
        float ekf = expf(acck[mi][ni][r] + bkv[ni]);
        acck[mi][ni][r] = ekf;
        accv[mi][ni][r] = ekf * (accv[mi][ni][r] + bvv[ni]);
      }
    }
  // pass 1: ek -> LDS transpose ([64 n][256+8 s]) -> EKT
#pragma unroll
  for (int mi = 0; mi < 4; mi++)
#pragma unroll
    for (int ni = 0; ni < 2; ni++) {
      int nloc = wn * 32 + ni * 16 + (lane & 15);
#pragma unroll
      for (int r = 0; r < 4; r++)
        lds[nloc * 264 + wm * 64 + mi * 16 + rbq + r] = f2bf(acck[mi][ni][r]);
    }
  __syncthreads();
#pragma unroll
  for (int it = 0; it < 4; it++) {
    int ch = it * 512 + tid;
    int nloc = ch >> 5, c8 = ch & 31;
    us8 v = *reinterpret_cast<const us8*>(lds + nloc * 264 + c8 * 8);
    *reinterpret_cast<us8*>(EKT + (bIdx * CHN + n0 + nloc) * SEQL + s0 + c8 * 8) = v;
  }
  __syncthreads();
  // pass 2: ekv -> LDS transpose -> EKVT
#pragma unroll
  for (int mi = 0; mi < 4; mi++)
#pragma unroll
    for (int ni = 0; ni < 2; ni++) {
      int nloc = wn * 32 + ni * 16 + (lane & 15);
#pragma unroll
      for (int r = 0; r < 4; r++)
        lds[nloc * 264 + wm * 64 + mi * 16 + rbq + r] = f2bf(accv[mi][ni][r]);
    }
  __syncthreads();
#pragma unroll
  for (int it = 0; it < 4; it++) {
    int ch = it * 512 + tid;
    int nloc = ch >> 5, c8 = ch & 31;
    us8 v = *reinterpret_cast<const us8*>(lds + nloc * 264 + c8 * 8);
    *reinterpret_cast<us8*>(EKVT + (bIdx * CHN + n0 + nloc) * SEQL + s0 + c8 * 8) = v;
  }
}

// ---------------- gemm_aft: BM=256(t), BN=128x{EKT,EKVT}, BK=64, 8 waves (2M x 4N) ----
// Wave tile 128x(32x2): 42.7 FLOP/LDS-byte.
__global__ __launch_bounds__(512, 2) void gemm_aft(
    const unsigned short* __restrict__ EB,
    const unsigned short* __restrict__ EKT, const unsigned short* __restrict__ EKVT,
    const unsigned short* __restrict__ Qb, float* __restrict__ out)
{
  __shared__ unsigned short lds[2 * 32768];  // per buf: A 256x64 (32K) | Bd 128x64 (16K) | Bn (16K)
  const int tid = threadIdx.x;
  const int lane = tid & 63;
  const int wid = tid >> 6;
  const int wm = wid >> 2;               // 0..1 -> 128-row strip
  const int wn = wid & 3;                // 0..3 -> 32-col strip per mat
  const int nwg = gridDim.x;             // 256
  const int lid = blockIdx.x;
  const int sid = (lid & 7) * (nwg >> 3) + (lid >> 3);
  const int t0 = (sid & 3) * 256;        // t fastest: B panels + EB L2-resident
  const int n0 = (sid >> 2) * 128;

  const unsigned short* srcA[4]; int dA[4];
#pragma unroll
  for (int p = 0; p < 4; p++) {
    int l = p * 8192 + tid * 16;
    int row = l >> 7;
    int lc = ((l >> 4) & 7) ^ (row & 7);
    srcA[p] = EB + (t0 + row) * SEQL + lc * 8;
    dA[p] = l >> 1;
  }
  const unsigned short* srcB[2][2]; int dB[2][2];
#pragma unroll
  for (int w = 0; w < 2; w++) {
    const unsigned short* B = (w == 0) ? EKT : EKVT;
#pragma unroll
    for (int p = 0; p < 2; p++) {
      int l = p * 8192 + tid * 16;
      int row = l >> 7;
      int lc = ((l >> 4) & 7) ^ (row & 7);
      srcB[w][p] = B + (n0 + row) * SEQL + lc * 8;
      dB[w][p] = 16384 + w * 8192 + (l >> 1);
    }
  }

  int aOff[8][2], bOff[2][2];
#pragma unroll
  for (int mi = 0; mi < 8; mi++) {
    int r = wm * 128 + mi * 16 + (lane & 15);
#pragma unroll
    for (int ks = 0; ks < 2; ks++)
      aOff[mi][ks] = r * 64 + ((((ks << 2) + (lane >> 4)) ^ (r & 7)) << 3);
  }
#pragma unroll
  for (int ni = 0; ni < 2; ni++) {
    int r = wn * 32 + ni * 16 + (lane & 15);
#pragma unroll
    for (int ks = 0; ks < 2; ks++)
      bOff[ni][ks] = r * 64 + ((((ks << 2) + (lane >> 4)) ^ (r & 7)) << 3);
  }

  f32x4 accd[8][2] = {}, accn[8][2] = {};

#pragma unroll
  for (int p = 0; p < 4; p++) gload16(srcA[p], lds + dA[p]);
#pragma unroll
  for (int w = 0; w < 2; w++)
#pragma unroll
    for (int p = 0; p < 2; p++) gload16(srcB[w][p], lds + dB[w][p]);

  for (int t = 0; t < 16; ++t) {
    const int cur = (t & 1) * 32768;
    const int nxt = 32768 - cur;
    const int kn = (t + 1) << 6;
    if (t < 15) {
#pragma unroll
      for (int p = 0; p < 4; p++) gload16(srcA[p] + kn, lds + nxt + dA[p]);
      // FIFO: [A(t) x4, B(t) x4, A(t+1) x4] -> keep 4 newest
      asm volatile("s_waitcnt vmcnt(4)" ::: "memory");
    } else {
      asm volatile("s_waitcnt vmcnt(0)" ::: "memory");
    }
    SBAR();
#pragma unroll
    for (int ks = 0; ks < 2; ks++) {
      bf16x8 bdf[2], bnf[2];
#pragma unroll
      for (int ni = 0; ni < 2; ni++) {
        bdf[ni] = *reinterpret_cast<const bf16x8*>(lds + cur + 16384 + bOff[ni][ks]);
        bnf[ni] = *reinterpret_cast<const bf16x8*>(lds + cur + 24576 + bOff[ni][ks]);
      }
      PRIO_HI();
#pragma unroll
      for (int mi = 0; mi < 8; mi++) {
        bf16x8 af = *reinterpret_cast<const bf16x8*>(lds + cur + aOff[mi][ks]);
#pragma unroll
        for (int ni = 0; ni < 2; ni++) {
          accd[mi][ni] = __builtin_amdgcn_mfma_f32_16x16x32_bf16(af, bdf[ni], accd[mi][ni], 0, 0, 0);
          accn[mi][ni] = __builtin_amdgcn_mfma_f32_16x16x32_bf16(af, bnf[ni], accn[mi][ni], 0, 0, 0);
        }
      }
      PRIO_LO();
      if (ks == 0 && t < 15) {
#pragma unroll
        for (int w = 0; w < 2; w++)
#pragma unroll
          for (int p = 0; p < 2; p++) gload16(srcB[w][p] + kn, lds + nxt + dB[w][p]);
      }
    }
    LGKM0();
    SBAR();
  }

  const int rbq = (lane >> 4) * 4;
#pragma unroll
  for (int mi = 0; mi < 8; mi++)
#pragma unroll
    for (int ni = 0; ni < 2; ni++) {
      int nloc = wn * 32 + ni * 16 + (lane & 15);
      int n = n0 + nloc;
      int b = n >> 10, c = n & 1023;
#pragma unroll
      for (int r = 0; r < 4; r++) {
        int tt = t0 + wm * 128 + mi * 16 + rbq + r;
        float qv = bf2f(Qb[(b * SEQL + tt) * CHN + c]);
        float sig = 1.0f / (1.0f + expf(-qv));
        out[(b * SEQL + tt) * CHN + c] = sig * accn[mi][ni][r] / accd[mi][ni][r];
      }
    }
}

extern "C" void kernel_launch(void* const* d_in, const int* in_sizes, int n_in,
                              void* d_out, int out_size, void* d_ws, size_t ws_size,
                              hipStream_t stream) {
  (void)in_sizes; (void)n_in; (void)out_size; (void)ws_size;
  const float* x    = (const float*)d_in[0];
  const float* wq   = (const float*)d_in[1];
  const float* wk   = (const float*)d_in[2];
  const float* wv   = (const float*)d_in[3];
  const float* bq   = (const float*)d_in[4];
  const float* bk   = (const float*)d_in[5];
  const float* bv   = (const float*)d_in[6];
  const float* bias = (const float*)d_in[7];
  float* out = (float*)d_out;

  char* ws = (char*)d_ws;
  const size_t MB = 1024 * 1024;
  unsigned short* Xb   = (unsigned short*)(ws);
  unsigned short* Wqb  = (unsigned short*)(ws + 16 * MB);
  unsigned short* Wkb  = (unsigned short*)(ws + 18 * MB);
  unsigned short* Wvb  = (unsigned short*)(ws + 20 * MB);
  unsigned short* EBb  = (unsigned short*)(ws + 22 * MB);
  unsigned short* Qb   = (unsigned short*)(ws + 24 * MB);
  unsigned short* EKT  = (unsigned short*)(ws + 40 * MB);
  unsigned short* EKVT = (unsigned short*)(ws + 56 * MB);

  prep_kernel<<<2048, 256, 0, stream>>>(x, wq, wk, wv, bias, Xb, Wqb, Wkb, Wvb, EBb);
  gemm_qkv<<<512, 512, 0, stream>>>(Xb, Wqb, Wkb, Wvb, bq, bk, bv, Qb, EKT, EKVT);
  gemm_aft<<<256, 512, 0, stream>>>(EBb, EKT, EKVT, Qb, out);
}